// Round 8
// baseline (572.014 us; speedup 1.0000x reference)
//
#include <hip/hip_runtime.h>
#include <math.h>

#define N_ENT 100000
#define N_USR 50000
#define N_TOT 150000
#define N_ROWS 250000     // unified rows: KG [0,N_ENT) + CF [N_ENT, N_ENT+N_TOT)
#define DD 64

#define SCAN_BLK 256
#define SCAN_ITEMS 1024   // elements per scan block

#define SORT_T 4096       // edges per phase-1 tile
#define BUK_SHIFT 8       // 256 rows per bucket
#define NBUKU 977         // ceil(N_ROWS / 256)
#define LDSCAP 5120       // phase-2 LDS segment capacity (KG bucket mean 3840, std ~62)

typedef _Float16 half8 __attribute__((ext_vector_type(8)));
typedef _Float16 half4 __attribute__((ext_vector_type(4)));
typedef _Float16 h2v __attribute__((ext_vector_type(2)));
typedef float floatx4 __attribute__((ext_vector_type(4)));

// ---------------------------------------------------------------------------
// Per-relation precompute: u_r = Wk_w[0:64]@r, v_r = Wk_w[64:128]@r, c_r = b@r
// uvr layout: [16][132]: u at 0..63, v at 64..127, c at 128
// ---------------------------------------------------------------------------
__global__ void k_rel(const float* __restrict__ Wk_w, const float* __restrict__ Wk_b,
                      const float* __restrict__ rel, float* __restrict__ uvr) {
    int r = blockIdx.x;   // 16 blocks
    int k = threadIdx.x;  // 128 threads
    const float* rv = rel + r * DD;
    const float* wrow = Wk_w + k * DD;
    float s = 0.f;
    for (int j = 0; j < DD; ++j) s += wrow[j] * rv[j];
    uvr[r * 132 + k] = s;
    if (k == 0) {
        float c = 0.f;
        for (int j = 0; j < DD; ++j) c += Wk_b[j] * rv[j];
        uvr[r * 132 + 128] = c;
    }
}

// ---------------------------------------------------------------------------
// Pack U[64][32] into fp16 MFMA B-fragment layout (4 KB). upack lives in the
// HEAD of pairbuf (dead until k_sort_fine) — do not grow the ws tail (round-3
// lesson: OOB past ws_size corrupts adjacent live buffers between phases).
// ---------------------------------------------------------------------------
__global__ void k_uvpack(const float* __restrict__ uvr, _Float16* __restrict__ upack) {
    int i = blockIdx.x * 256 + threadIdx.x;
    if (i >= 2048) return;
    int kstep = i >> 10;
    int rem = i & 1023;
    int ntile = rem >> 9;
    int rem2 = rem & 511;
    int lane = rem2 >> 3;
    int j = rem2 & 7;
    int k = kstep * 32 + (lane >> 4) * 8 + j;
    upack[i] = (_Float16)uvr[(lane & 15) * 132 + ntile * 64 + k];
}

// ---------------------------------------------------------------------------
// Per-entity projections as MFMA GEMM: Puv[100000x32] = e16[100000x64] @ U.
// One wave = 16 rows, 4x mfma_f32_16x16x32_f16 (57us serial-fmaf -> ~8us).
// ---------------------------------------------------------------------------
__global__ __launch_bounds__(256) void k_proj(const _Float16* __restrict__ e16,
        const _Float16* __restrict__ upack, float* __restrict__ Puv) {
    int lane = threadIdx.x & 63;
    int wv = (blockIdx.x * 256 + threadIdx.x) >> 6;
    int row0 = wv * 16;
    if (row0 >= N_ENT) return;
    int m = lane & 15;
    int quad = lane >> 4;

    const _Float16* er = e16 + (size_t)(row0 + m) * DD + quad * 8;
    half8 a0 = *(const half8*)(er);        // k = 0..31 slice
    half8 a1 = *(const half8*)(er + 32);   // k = 32..63 slice

    const half8* up = (const half8*)upack;
    half8 b00 = up[0 * 128 + 0 * 64 + lane];   // kstep0, ntile0
    half8 b01 = up[0 * 128 + 1 * 64 + lane];   // kstep0, ntile1
    half8 b10 = up[1 * 128 + 0 * 64 + lane];   // kstep1, ntile0
    half8 b11 = up[1 * 128 + 1 * 64 + lane];   // kstep1, ntile1

    floatx4 c0 = {0.f, 0.f, 0.f, 0.f};
    floatx4 c1 = {0.f, 0.f, 0.f, 0.f};
    c0 = __builtin_amdgcn_mfma_f32_16x16x32_f16(a0, b00, c0, 0, 0, 0);
    c0 = __builtin_amdgcn_mfma_f32_16x16x32_f16(a1, b10, c0, 0, 0, 0);
    c1 = __builtin_amdgcn_mfma_f32_16x16x32_f16(a0, b01, c1, 0, 0, 0);
    c1 = __builtin_amdgcn_mfma_f32_16x16x32_f16(a1, b11, c1, 0, 0, 0);

    // C/D: row = quad*4 + r, col = ntile*16 + m  [k_gate3-verified layout]
#pragma unroll
    for (int r = 0; r < 4; ++r) {
        size_t row = (size_t)(row0 + quad * 4 + r);
        Puv[row * 32 + m] = c0[r];
        Puv[row * 32 + 16 + m] = c1[r];
    }
}

// ---------------------------------------------------------------------------
// Sort phase 0: per-tile bucket histogram. tilecnt[b * NT + tile] = count.
// ---------------------------------------------------------------------------
__global__ __launch_bounds__(256) void k_sort_hist(const int* __restrict__ kg_h,
        const int* __restrict__ ain_row, int* __restrict__ tilecnt,
        int E_KG, int E_TOT, int NT) {
    __shared__ int hist[1024];
#pragma unroll
    for (int k = 0; k < 4; ++k) hist[k * 256 + threadIdx.x] = 0;
    __syncthreads();
    int tile = blockIdx.x;
    int base = tile * SORT_T;
#pragma unroll
    for (int k = 0; k < SORT_T / 256; ++k) {
        int e = base + k * 256 + threadIdx.x;
        if (e < E_TOT) {
            int row = (e < E_KG) ? kg_h[e] : (N_ENT + ain_row[e - E_KG]);
            atomicAdd(&hist[row >> BUK_SHIFT], 1);
        }
    }
    __syncthreads();
    for (int b = threadIdx.x; b < NBUKU; b += 256)
        tilecnt[b * NT + tile] = hist[b];
}

// --- multi-block exclusive scan, phase 1: per-chunk partial sums ---
__global__ __launch_bounds__(SCAN_BLK) void k_blocksum(const int* __restrict__ cnt,
                                                       int* __restrict__ bsum, int n) {
    __shared__ int s[SCAN_BLK];
    int base = blockIdx.x * SCAN_ITEMS;
    int sum = 0;
    for (int i = threadIdx.x; i < SCAN_ITEMS; i += SCAN_BLK) {
        int idx = base + i;
        if (idx < n) sum += cnt[idx];
    }
    s[threadIdx.x] = sum;
    __syncthreads();
    for (int off = SCAN_BLK / 2; off; off >>= 1) {
        if (threadIdx.x < off) s[threadIdx.x] += s[threadIdx.x + off];
        __syncthreads();
    }
    if (threadIdx.x == 0) bsum[blockIdx.x] = s[0];
}

// --- phase 2: single-block exclusive scan of partials (nb <= 1024) ---
__global__ __launch_bounds__(1024) void k_bscan(int* __restrict__ bsum, int nb,
                                                int* __restrict__ total_out) {
    __shared__ int s[1024];
    int tid = threadIdx.x;
    int v = (tid < nb) ? bsum[tid] : 0;
    s[tid] = v;
    __syncthreads();
    for (int off = 1; off < 1024; off <<= 1) {
        int t = (tid >= off) ? s[tid - off] : 0;
        __syncthreads();
        s[tid] += t;
        __syncthreads();
    }
    if (tid < nb) bsum[tid] = s[tid] - v;   // exclusive
    if (tid == 1023) *total_out = s[1023];
}

// --- phase 3: block-local scan + offset; writes scanned values ---
__global__ __launch_bounds__(SCAN_BLK) void k_scan_apply(const int* __restrict__ cnt,
        int* __restrict__ scanned, const int* __restrict__ bsum, int n) {
    __shared__ int s[SCAN_BLK];
    int base = blockIdx.x * SCAN_ITEMS;
    int t = threadIdx.x;
    int idx0 = base + t * 4;
    int v[4];
    int lsum = 0;
#pragma unroll
    for (int k = 0; k < 4; ++k) {
        int idx = idx0 + k;
        v[k] = (idx < n) ? cnt[idx] : 0;
        lsum += v[k];
    }
    s[t] = lsum;
    __syncthreads();
    for (int off = 1; off < SCAN_BLK; off <<= 1) {
        int tv = (t >= off) ? s[t - off] : 0;
        __syncthreads();
        s[t] += tv;
        __syncthreads();
    }
    int pre = (t ? s[t - 1] : 0) + bsum[blockIdx.x];
#pragma unroll
    for (int k = 0; k < 4; ++k) {
        int idx = idx0 + k;
        if (idx < n) scanned[idx] = pre;
        pre += v[k];
    }
}

// ---------------------------------------------------------------------------
// Sort phase 1: tile-local LDS counting sort, then bucket-run coalesced writes.
// Payload: KG: x = t | r<<17 | rlow<<22, y = junk (filled by fused softmax)
//          CF: x = col | rlow<<22,       y = bits(val)        (rlow = row&255)
// Global slot contract: bucket b's tile-run starts at tilescan[b*NT+tile].
// ---------------------------------------------------------------------------
__global__ __launch_bounds__(256) void k_sort_scatter(const int* __restrict__ kg_h,
        const int* __restrict__ kg_t, const int* __restrict__ kg_r,
        const int* __restrict__ ain_row, const int* __restrict__ ain_col,
        const float* __restrict__ ain_val, const int* __restrict__ tilescan,
        int2* __restrict__ bufA, int E_KG, int E_TOT, int NT) {
    __shared__ int2 seg[SORT_T];      // 32 KB: bucket-sorted payloads
    __shared__ short sbuk[SORT_T];    // 8 KB: bucket id per seg slot
    __shared__ int hist[1024];        // counts -> then gadj = gbase - excl
    __shared__ int cur[1024];         // scatter cursors (start at excl)
    __shared__ int ssum[256];         // scan temp
    int tid = threadIdx.x;
    int tile = blockIdx.x;
#pragma unroll
    for (int k = 0; k < 4; ++k) hist[k * 256 + tid] = 0;
    __syncthreads();

    int base = tile * SORT_T;
    int px[SORT_T / 256], py[SORT_T / 256];
    short pb[SORT_T / 256];
#pragma unroll
    for (int k = 0; k < SORT_T / 256; ++k) {
        int e = base + k * 256 + tid;
        int x = 0, y = 0, b = -1;
        if (e < E_TOT) {
            int row;
            if (e < E_KG) {
                row = kg_h[e];
                x = kg_t[e] | (kg_r[e] << 17) | ((row & 255) << 22);
                y = 0;
            } else {
                int i = e - E_KG;
                row = N_ENT + ain_row[i];
                x = ain_col[i] | ((row & 255) << 22);
                y = __float_as_int(ain_val[i]);
            }
            b = row >> BUK_SHIFT;
            atomicAdd(&hist[b], 1);
        }
        px[k] = x; py[k] = y; pb[k] = (short)b;
    }
    __syncthreads();

    // exclusive scan of hist[0..1023]: thread t owns buckets 4t..4t+3.
    // Afterwards: cur[b] = local excl prefix, hist[b] = gbase[b] - excl[b].
    {
        int b0 = 4 * tid;
        int v0 = hist[b0], v1 = hist[b0 + 1], v2 = hist[b0 + 2], v3 = hist[b0 + 3];
        int g0 = (b0     < NBUKU) ? tilescan[(b0    ) * NT + tile] : 0;
        int g1 = (b0 + 1 < NBUKU) ? tilescan[(b0 + 1) * NT + tile] : 0;
        int g2 = (b0 + 2 < NBUKU) ? tilescan[(b0 + 2) * NT + tile] : 0;
        int g3 = (b0 + 3 < NBUKU) ? tilescan[(b0 + 3) * NT + tile] : 0;
        int lsum = v0 + v1 + v2 + v3;
        ssum[tid] = lsum;
        __syncthreads();
        for (int off = 1; off < 256; off <<= 1) {
            int t = (tid >= off) ? ssum[tid - off] : 0;
            __syncthreads();
            ssum[tid] += t;
            __syncthreads();
        }
        int ex = ssum[tid] - lsum;   // exclusive over thread groups
        cur[b0] = ex;     hist[b0] = g0 - ex;     ex += v0;
        cur[b0 + 1] = ex; hist[b0 + 1] = g1 - ex; ex += v1;
        cur[b0 + 2] = ex; hist[b0 + 2] = g2 - ex; ex += v2;
        cur[b0 + 3] = ex; hist[b0 + 3] = g3 - ex;
    }
    __syncthreads();

    // LDS scatter into bucket-sorted order
#pragma unroll
    for (int k = 0; k < SORT_T / 256; ++k) {
        if (pb[k] >= 0) {
            int slot = atomicAdd(&cur[pb[k]], 1);
            seg[slot] = make_int2(px[k], py[k]);
            sbuk[slot] = pb[k];
        }
    }
    __syncthreads();

    // coalesced write-out: consecutive i in the same bucket -> consecutive
    // global addresses (addr = gbase[b] + (i - excl[b]) = hist[b] + i)
    int cnt = min(SORT_T, E_TOT - base);
    for (int i = tid; i < cnt; i += 256) {
        int b = sbuk[i];
        bufA[hist[b] + i] = seg[i];
    }
}

// ---------------------------------------------------------------------------
// Sort phase 2 + FUSED SEGMENT SOFTMAX. One block per bucket (256 rows).
// rlow-only key (round-6: coltile key was FETCH-neutral, cost +6us).
// ---------------------------------------------------------------------------
__global__ __launch_bounds__(256) void k_sort_fine(const int* __restrict__ tilescan,
        const int2* __restrict__ bufA, int2* __restrict__ pairbuf,
        int* __restrict__ rowptr, const float* __restrict__ Puv,
        const float* __restrict__ uvr, int NT) {
    __shared__ int2 seg[LDSCAP];    // 40 KB
    __shared__ int rcnt[256];
    __shared__ int rexc[256];
    __shared__ int rcur[256];
    __shared__ float rsum[256];
    __shared__ float c16[16];
    int tid = threadIdx.x;
    int b = blockIdx.x;
    rcnt[tid] = 0;
    rsum[tid] = 0.f;
    if (tid < 16) c16[tid] = uvr[tid * 132 + 128];
    __syncthreads();

    int base = tilescan[b * NT];
    int endo = tilescan[(b + 1) * NT];
    int bsize = endo - base;
    int growbase = b << BUK_SHIFT;

    for (int i = base + tid; i < endo; i += 256) {
        unsigned rlow = ((unsigned)bufA[i].x) >> 22;
        atomicAdd(&rcnt[rlow], 1);
    }
    __syncthreads();

    {
        int v = rcnt[tid];
        rexc[tid] = v;
        __syncthreads();
        for (int off = 1; off < 256; off <<= 1) {
            int t = (tid >= off) ? rexc[tid - off] : 0;
            __syncthreads();
            rexc[tid] += t;
            __syncthreads();
        }
        int ex = rexc[tid] - v;     // exclusive
        rexc[tid] = ex;
        rcur[tid] = ex;
        int row = growbase + tid;
        if (row <= N_ROWS) rowptr[row] = base + ex;
    }
    __syncthreads();

    if (bsize <= LDSCAP) {
        for (int i = base + tid; i < endo; i += 256) {
            int2 p = bufA[i];
            unsigned rlow = ((unsigned)p.x) >> 22;
            seg[atomicAdd(&rcur[rlow], 1)] = p;
        }
        __syncthreads();
        for (int i = tid; i < bsize; i += 256) {
            int2 p = seg[i];
            unsigned rlow = ((unsigned)p.x) >> 22;
            int grow = growbase + (int)rlow;
            if (grow < N_ENT) {
                int t = p.x & 0x1FFFF;
                int r = (p.x >> 17) & 15;
                float lg = Puv[(size_t)t * 32 + r] + Puv[(size_t)grow * 32 + 16 + r] + c16[r];
                lg = lg >= 0.f ? lg : 0.01f * lg;
                // softmax is shift-invariant; |logit| << 1 so skip segment-max
                float exv = expf(lg);
                seg[i].y = __float_as_int(exv);
                atomicAdd(&rsum[rlow], exv);
            }
        }
        __syncthreads();
        rsum[tid] = 1.f / rsum[tid];   // unused for CF/empty rows
        __syncthreads();
        for (int i = tid; i < bsize; i += 256) {
            int2 p = seg[i];
            unsigned rlow = ((unsigned)p.x) >> 22;
            if (growbase + (int)rlow < N_ENT)
                p.y = __float_as_int(__int_as_float(p.y) * rsum[rlow]);
            pairbuf[base + i] = p;
        }
    } else {
        for (int i = base + tid; i < endo; i += 256) {
            int2 p = bufA[i];
            unsigned rlow = ((unsigned)p.x) >> 22;
            int slot = atomicAdd(&rcur[rlow], 1);
            pairbuf[base + slot] = p;
        }
        __syncthreads();
        for (int i = base + tid; i < endo; i += 256) {
            int2 p = pairbuf[i];
            unsigned rlow = ((unsigned)p.x) >> 22;
            int grow = growbase + (int)rlow;
            if (grow < N_ENT) {
                int t = p.x & 0x1FFFF;
                int r = (p.x >> 17) & 15;
                float lg = Puv[(size_t)t * 32 + r] + Puv[(size_t)grow * 32 + 16 + r] + c16[r];
                lg = lg >= 0.f ? lg : 0.01f * lg;
                float exv = expf(lg);
                pairbuf[i].y = __float_as_int(exv);
                atomicAdd(&rsum[rlow], exv);
            }
        }
        __syncthreads();
        rsum[tid] = 1.f / rsum[tid];
        __syncthreads();
        for (int i = base + tid; i < endo; i += 256) {
            int2 p = pairbuf[i];
            unsigned rlow = ((unsigned)p.x) >> 22;
            if (growbase + (int)rlow < N_ENT)
                pairbuf[i].y = __float_as_int(__int_as_float(p.y) * rsum[rlow]);
        }
    }
}

// ---------------------------------------------------------------------------
// Pack Wa,Wb into fp16 MFMA B-fragment layout (16 KB).
// ---------------------------------------------------------------------------
__global__ void k_wcvt(const float* __restrict__ Wa, const float* __restrict__ Wb,
                       _Float16* __restrict__ wpack) {
    int i = blockIdx.x * 256 + threadIdx.x;
    if (i >= 8192) return;
    int m = i >> 12;
    int rem = i & 4095;
    int kstep = rem >> 11;
    int rem2 = rem & 2047;
    int ntile = rem2 >> 9;
    int rem3 = rem2 & 511;
    int lane = rem3 >> 3;
    int j = rem3 & 7;
    int k = kstep * 32 + (lane >> 4) * 8 + j;
    int n = ntile * 16 + (lane & 15);
    const float* W = m ? Wb : Wa;
    wpack[i] = (_Float16)W[k * 64 + n];
}

// ---------------------------------------------------------------------------
// MERGED PAIRED-ROW CSR SpMM v2. Round-7 counters: merging raised achieved BW
// 3.33->3.54 TB/s (FETCH = exact sum of parts) -> the gather stream responds
// to memory-level parallelism, not yet at a hard fabric ceiling. v2 levers:
// (1) unroll 8 (8 gathers in flight/wave-half vs 4; VGPR 20->~50, still
//     8 blocks/CU), (2) nontemporal pairbuf loads: the 24MB single-use
//     payload stream bypasses L2, reserving it for x-rows with ~10-15x
//     reuse potential (measured hit 16% < 21% capacity bound -> pollution).
// ---------------------------------------------------------------------------
__global__ __launch_bounds__(256) void k_spmm2(const int* __restrict__ rowptr,
        const int2* __restrict__ pairbuf, const _Float16* __restrict__ xkg,
        const _Float16* __restrict__ xcf, _Float16* __restrict__ outkg,
        _Float16* __restrict__ outcf, int row_begin) {
    int wid0 = (blockIdx.x * 256 + threadIdx.x) >> 6;
    int wpair = __builtin_amdgcn_readfirstlane(wid0);
    int lane = threadIdx.x & 63;
    int half = lane >> 5;
    int sub = lane & 31;
    int row = row_begin + wpair * 2 + half;
    if (row >= N_ROWS) return;
    int d0 = sub * 2;
    bool kg = row < N_ENT;
    const _Float16* xb = (kg ? xkg : xcf) + d0;
    int cmask = kg ? 0x1FFFF : 0x3FFFF;
    _Float16* ob = kg ? (outkg + (size_t)row * DD)
                      : (outcf + (size_t)(row - N_ENT) * DD);
    const long long* pb64 = (const long long*)pairbuf;
    int s = rowptr[row], e = rowptr[row + 1];
    float a00 = 0.f, a01 = 0.f, a10 = 0.f, a11 = 0.f;
    float a20 = 0.f, a21 = 0.f, a30 = 0.f, a31 = 0.f;
    float a40 = 0.f, a41 = 0.f, a50 = 0.f, a51 = 0.f;
    float a60 = 0.f, a61 = 0.f, a70 = 0.f, a71 = 0.f;
    int i = s;
    for (; i + 8 <= e; i += 8) {
        long long q0 = __builtin_nontemporal_load(pb64 + i);
        long long q1 = __builtin_nontemporal_load(pb64 + i + 1);
        long long q2 = __builtin_nontemporal_load(pb64 + i + 2);
        long long q3 = __builtin_nontemporal_load(pb64 + i + 3);
        long long q4 = __builtin_nontemporal_load(pb64 + i + 4);
        long long q5 = __builtin_nontemporal_load(pb64 + i + 5);
        long long q6 = __builtin_nontemporal_load(pb64 + i + 6);
        long long q7 = __builtin_nontemporal_load(pb64 + i + 7);
        h2v g0 = *(const h2v*)(xb + (size_t)((int)q0 & cmask) * DD);
        h2v g1 = *(const h2v*)(xb + (size_t)((int)q1 & cmask) * DD);
        h2v g2 = *(const h2v*)(xb + (size_t)((int)q2 & cmask) * DD);
        h2v g3 = *(const h2v*)(xb + (size_t)((int)q3 & cmask) * DD);
        h2v g4 = *(const h2v*)(xb + (size_t)((int)q4 & cmask) * DD);
        h2v g5 = *(const h2v*)(xb + (size_t)((int)q5 & cmask) * DD);
        h2v g6 = *(const h2v*)(xb + (size_t)((int)q6 & cmask) * DD);
        h2v g7 = *(const h2v*)(xb + (size_t)((int)q7 & cmask) * DD);
        float w0 = __int_as_float((int)(q0 >> 32));
        float w1 = __int_as_float((int)(q1 >> 32));
        float w2 = __int_as_float((int)(q2 >> 32));
        float w3 = __int_as_float((int)(q3 >> 32));
        float w4 = __int_as_float((int)(q4 >> 32));
        float w5 = __int_as_float((int)(q5 >> 32));
        float w6 = __int_as_float((int)(q6 >> 32));
        float w7 = __int_as_float((int)(q7 >> 32));
        a00 = fmaf(w0, (float)g0[0], a00); a01 = fmaf(w0, (float)g0[1], a01);
        a10 = fmaf(w1, (float)g1[0], a10); a11 = fmaf(w1, (float)g1[1], a11);
        a20 = fmaf(w2, (float)g2[0], a20); a21 = fmaf(w2, (float)g2[1], a21);
        a30 = fmaf(w3, (float)g3[0], a30); a31 = fmaf(w3, (float)g3[1], a31);
        a40 = fmaf(w4, (float)g4[0], a40); a41 = fmaf(w4, (float)g4[1], a41);
        a50 = fmaf(w5, (float)g5[0], a50); a51 = fmaf(w5, (float)g5[1], a51);
        a60 = fmaf(w6, (float)g6[0], a60); a61 = fmaf(w6, (float)g6[1], a61);
        a70 = fmaf(w7, (float)g7[0], a70); a71 = fmaf(w7, (float)g7[1], a71);
    }
    for (; i + 2 <= e; i += 2) {
        long long q0 = __builtin_nontemporal_load(pb64 + i);
        long long q1 = __builtin_nontemporal_load(pb64 + i + 1);
        h2v g0 = *(const h2v*)(xb + (size_t)((int)q0 & cmask) * DD);
        h2v g1 = *(const h2v*)(xb + (size_t)((int)q1 & cmask) * DD);
        float w0 = __int_as_float((int)(q0 >> 32));
        float w1 = __int_as_float((int)(q1 >> 32));
        a00 = fmaf(w0, (float)g0[0], a00); a01 = fmaf(w0, (float)g0[1], a01);
        a10 = fmaf(w1, (float)g1[0], a10); a11 = fmaf(w1, (float)g1[1], a11);
    }
    if (i < e) {
        long long q0 = __builtin_nontemporal_load(pb64 + i);
        h2v g0 = *(const h2v*)(xb + (size_t)((int)q0 & cmask) * DD);
        float w0 = __int_as_float((int)(q0 >> 32));
        a00 = fmaf(w0, (float)g0[0], a00); a01 = fmaf(w0, (float)g0[1], a01);
    }
    float r0 = ((a00 + a10) + (a20 + a30)) + ((a40 + a50) + (a60 + a70));
    float r1 = ((a01 + a11) + (a21 + a31)) + ((a41 + a51) + (a61 + a71));
    h2v st; st[0] = (_Float16)r0; st[1] = (_Float16)r1;
    *(h2v*)(ob + d0) = st;
}

// ---------------------------------------------------------------------------
// Entity gate via MFMA (one wave = 16 rows), FUSED with user passthrough copy:
// blocks >= ngate copy ig16 user rows into dual16 (half8).
// acc = kg@Wa + ig@Wb in one accumulator chain.
// C/D: col=lane&15, row=(lane>>4)*4+reg [m89-verified].
// ---------------------------------------------------------------------------
__global__ __launch_bounds__(256) void k_gate3(const _Float16* __restrict__ kg16,
        const _Float16* __restrict__ ig16, const _Float16* __restrict__ wpack,
        _Float16* __restrict__ dual16, int ngate) {
    __shared__ _Float16 sw[8192];
    if ((int)blockIdx.x >= ngate) {
        int i = ((int)blockIdx.x - ngate) * 256 + threadIdx.x;
        if (i < N_USR * DD / 8) {
            size_t o = (size_t)N_ENT * DD / 8 + i;
            ((half8*)dual16)[o] = ((const half8*)ig16)[o];
        }
        return;
    }
    for (int i = threadIdx.x * 8; i < 8192; i += 256 * 8)
        *(half8*)(sw + i) = *(const half8*)(wpack + i);
    __syncthreads();
    int lane = threadIdx.x & 63;
    int wv = (blockIdx.x * 256 + threadIdx.x) >> 6;
    int row0 = wv * 16;
    if (row0 >= N_ENT) return;
    int m = lane & 15;
    int quad = lane >> 4;

    const _Float16* kgr = kg16 + (size_t)(row0 + m) * DD + quad * 8;
    const _Float16* igr = ig16 + (size_t)(row0 + m) * DD + quad * 8;
    half8 akg0 = *(const half8*)(kgr);
    half8 akg1 = *(const half8*)(kgr + 32);
    half8 aig0 = *(const half8*)(igr);
    half8 aig1 = *(const half8*)(igr + 32);

    floatx4 acc[4];
#pragma unroll
    for (int t = 0; t < 4; ++t) {
        half8 bA0 = *(const half8*)(sw + 0 * 4096 + 0 * 2048 + t * 512 + lane * 8);
        half8 bA1 = *(const half8*)(sw + 0 * 4096 + 1 * 2048 + t * 512 + lane * 8);
        half8 bB0 = *(const half8*)(sw + 1 * 4096 + 0 * 2048 + t * 512 + lane * 8);
        half8 bB1 = *(const half8*)(sw + 1 * 4096 + 1 * 2048 + t * 512 + lane * 8);
        floatx4 c = {0.f, 0.f, 0.f, 0.f};
        c = __builtin_amdgcn_mfma_f32_16x16x32_f16(akg0, bA0, c, 0, 0, 0);
        c = __builtin_amdgcn_mfma_f32_16x16x32_f16(akg1, bA1, c, 0, 0, 0);
        c = __builtin_amdgcn_mfma_f32_16x16x32_f16(aig0, bB0, c, 0, 0, 0);
        c = __builtin_amdgcn_mfma_f32_16x16x32_f16(aig1, bB1, c, 0, 0, 0);
        acc[t] = c;
    }

#pragma unroll
    for (int t = 0; t < 4; ++t) {
#pragma unroll
        for (int r = 0; r < 4; ++r) {
            int row = quad * 4 + r;
            int col = t * 16 + m;
            size_t o = (size_t)(row0 + row) * DD + col;
            float kv = (float)kg16[o];
            float cv = (float)ig16[o];
            float g = 1.f / (1.f + expf(-acc[t][r]));
            dual16[o] = (_Float16)(g * kv + (1.f - g) * cv);
        }
    }
}

// init: dual16 = fp16(embed)
__global__ void k_init(const float* __restrict__ embed, _Float16* __restrict__ dual16) {
    int i = blockIdx.x * blockDim.x + threadIdx.x;
    if (i >= N_TOT * DD) return;
    dual16[i] = (_Float16)embed[i];
}

// ---------------------------------------------------------------------------
// out[u,j] = sums[user_ids[u]] . sums[item_ids[j]],
// sums[row] = embed[row] + ig0[row] + ig1[row] + ig2[row] (reconstructed).
// 256 blocks: 32 user-groups (32 users) x 8 item-chunks (256 items).
// ---------------------------------------------------------------------------
__global__ __launch_bounds__(256) void k_out(const float* __restrict__ embed,
        const _Float16* __restrict__ ig0, const _Float16* __restrict__ ig1,
        const _Float16* __restrict__ ig2, const int* __restrict__ user_ids,
        const int* __restrict__ item_ids, float* __restrict__ out) {
    __shared__ float uvec[32 * DD];
    int ug = blockIdx.x >> 3;
    int qi = blockIdx.x & 7;
    int ub = ug * 32;
    for (int i = threadIdx.x; i < 32 * DD; i += 256) {
        int uu = i >> 6, d = i & 63;
        size_t o = (size_t)user_ids[ub + uu] * DD + d;
        uvec[i] = embed[o] + (float)ig0[o] + (float)ig1[o] + (float)ig2[o];
    }
    __syncthreads();
    int jbase = qi * 256;
    for (int j = threadIdx.x; j < 256; j += 256) {
        size_t ro = (size_t)item_ids[jbase + j] * DD;
        float acc[32];
#pragma unroll
        for (int u = 0; u < 32; ++u) acc[u] = 0.f;
        for (int d = 0; d < DD; d += 4) {
            float4 ev = *(const float4*)(embed + ro + d);
            half4 h0 = *(const half4*)(ig0 + ro + d);
            half4 h1 = *(const half4*)(ig1 + ro + d);
            half4 h2 = *(const half4*)(ig2 + ro + d);
            float iv0 = ev.x + (float)h0[0] + (float)h1[0] + (float)h2[0];
            float iv1 = ev.y + (float)h0[1] + (float)h1[1] + (float)h2[1];
            float iv2 = ev.z + (float)h0[2] + (float)h1[2] + (float)h2[2];
            float iv3 = ev.w + (float)h0[3] + (float)h1[3] + (float)h2[3];
#pragma unroll
            for (int u = 0; u < 32; ++u) {
                acc[u] = fmaf(iv0, uvec[u * DD + d + 0], acc[u]);
                acc[u] = fmaf(iv1, uvec[u * DD + d + 1], acc[u]);
                acc[u] = fmaf(iv2, uvec[u * DD + d + 2], acc[u]);
                acc[u] = fmaf(iv3, uvec[u * DD + d + 3], acc[u]);
            }
        }
#pragma unroll
        for (int u = 0; u < 32; ++u)
            out[(size_t)(ub + u) * 2048 + jbase + j] = acc[u];
    }
}

extern "C" void kernel_launch(void* const* d_in, const int* in_sizes, int n_in,
                              void* d_out, int out_size, void* d_ws, size_t ws_size,
                              hipStream_t stream) {
    const float* embed   = (const float*)d_in[0];
    const float* rel     = (const float*)d_in[1];
    const float* Wk_w    = (const float*)d_in[2];
    const float* Wk_b    = (const float*)d_in[3];
    const float* Wa      = (const float*)d_in[4];
    const float* Wb      = (const float*)d_in[5];
    const int*   kg_h    = (const int*)d_in[6];
    const int*   kg_t    = (const int*)d_in[7];
    const int*   kg_r    = (const int*)d_in[8];
    const int*   ain_row = (const int*)d_in[9];
    const int*   ain_col = (const int*)d_in[10];
    const float* ain_val = (const float*)d_in[11];
    const int*   user_ids = (const int*)d_in[12];
    const int*   item_ids = (const int*)d_in[13];
    int E_KG = in_sizes[6];
    int E_CF = in_sizes[9];
    int E_TOT = E_KG + E_CF;
    float* out = (float*)d_out;

    int NT  = (E_TOT + SORT_T - 1) / SORT_T;   // phase-1 tiles (733)
    int NTC = NBUKU * NT;                       // scan length (~716K)

    float* ws = (float*)d_ws;
    size_t off = 0;
    float* uvr       = ws + off; off += 16 * 132;
    float* Puv       = ws + off; off += (size_t)N_ENT * 32;
    int*   rowptr    = (int*)(ws + off); off += N_ROWS + 4;
    int*   tilecnt   = (int*)(ws + off); off += (size_t)NTC + 4;
    int*   tilescan  = (int*)(ws + off); off += (size_t)NTC + 4;
    int*   bsum      = (int*)(ws + off); off += 1024;
    int2*  pairbuf   = (int2*)(ws + off); off += 2 * (size_t)E_TOT;   // final (row-sorted)
    _Float16* dual16 = (_Float16*)(ws + off); off += (size_t)N_TOT * DD / 2;
    _Float16* ig16_0 = (_Float16*)(ws + off); off += (size_t)N_TOT * DD / 2;
    _Float16* ig16_1 = (_Float16*)(ws + off); off += (size_t)N_TOT * DD / 2;
    _Float16* ig16_2 = (_Float16*)(ws + off); off += (size_t)N_TOT * DD / 2;
    _Float16* kg16A  = (_Float16*)(ws + off); off += (size_t)N_ENT * DD / 2;
    _Float16* kg16B  = (_Float16*)(ws + off); off += (size_t)N_ENT * DD / 2;
    _Float16* wpack  = (_Float16*)(ws + off); off += 8192 / 2;
    int2*  bufA      = (int2*)kg16A;   // alias: 24MB <= kg16A+kg16B (25.6MB); dead before layer0
    // upack aliases the HEAD of pairbuf (4 KB): written by k_uvpack, read by
    // k_proj, both strictly before k_sort_fine first writes pairbuf. Keeps the
    // ws footprint identical to the harness-verified round-0/1 layout (no tail
    // growth -> no OOB past ws_size).
    _Float16* upack  = (_Float16*)pairbuf;
    _Float16* ig_l[3] = {ig16_0, ig16_1, ig16_2};

    // --- attention precompute (needed by fused sort+softmax) ---
    // k_init first: dual16 (fp16 embed) feeds the MFMA k_proj.
    hipLaunchKernelGGL(k_init, dim3((N_TOT * DD + 255) / 256), dim3(256), 0, stream,
                       embed, dual16);
    hipLaunchKernelGGL(k_rel, dim3(16), dim3(128), 0, stream, Wk_w, Wk_b, rel, uvr);
    hipLaunchKernelGGL(k_uvpack, dim3(8), dim3(256), 0, stream, uvr, upack);
    hipLaunchKernelGGL(k_proj, dim3((N_ENT / 16 + 3) / 4), dim3(256), 0, stream,
                       dual16, upack, Puv);

    // --- binning sort: hist -> scan -> tile scatter -> fine sort + softmax ---
    hipLaunchKernelGGL(k_sort_hist, dim3(NT), dim3(256), 0, stream,
                       kg_h, ain_row, tilecnt, E_KG, E_TOT, NT);
    int nb = (NTC + SCAN_ITEMS - 1) / SCAN_ITEMS;   // ~700
    hipLaunchKernelGGL(k_blocksum, dim3(nb), dim3(SCAN_BLK), 0, stream, tilecnt, bsum, NTC);
    hipLaunchKernelGGL(k_bscan, dim3(1), dim3(1024), 0, stream, bsum, nb, tilescan + NTC);
    hipLaunchKernelGGL(k_scan_apply, dim3(nb), dim3(SCAN_BLK), 0, stream,
                       tilecnt, tilescan, bsum, NTC);
    hipLaunchKernelGGL(k_sort_scatter, dim3(NT), dim3(256), 0, stream,
                       kg_h, kg_t, kg_r, ain_row, ain_col, ain_val, tilescan,
                       bufA, E_KG, E_TOT, NT);
    hipLaunchKernelGGL(k_sort_fine, dim3(NBUKU), dim3(256), 0, stream,
                       tilescan, bufA, pairbuf, rowptr, Puv, uvr, NT);

    hipLaunchKernelGGL(k_wcvt, dim3(32), dim3(256), 0, stream, Wa, Wb, wpack);

    // --- 3 propagation layers; layers 0/1 use the MERGED KG+CF spmm ---
    const _Float16* cur16 = dual16;       // layer0 KG gather table = fp16 embed
    _Float16* kg16o = kg16A;
    _Float16* kg16alt = kg16B;
    int all_blocks = ((N_ROWS / 2) * 64 + 255) / 256;   // 31250
    int cf_blocks = ((N_TOT / 2) * 64 + 255) / 256;     // 18750
    int ngate = (N_ENT / 16 + 3) / 4;                   // 1563
    int nuc = (N_USR * DD / 8 + 255) / 256;             // 1563
    for (int layer = 0; layer < 3; ++layer) {
        if (layer < 2) {
            hipLaunchKernelGGL(k_spmm2, dim3(all_blocks), dim3(256), 0, stream,
                               rowptr, pairbuf, cur16, dual16, kg16o, ig_l[layer], 0);
            hipLaunchKernelGGL(k_gate3, dim3(ngate + nuc), dim3(256), 0, stream,
                               kg16o, ig_l[layer], wpack, dual16, ngate);
            cur16 = kg16o;
            kg16o = kg16alt;
            kg16alt = (_Float16*)cur16;
        } else {
            hipLaunchKernelGGL(k_spmm2, dim3(cf_blocks), dim3(256), 0, stream,
                               rowptr, pairbuf, dual16, dual16, kg16o, ig_l[layer], N_ENT);
        }
    }

    // --- final gather-GEMM 1024 x 2048 x 64 with on-the-fly sums ---
    hipLaunchKernelGGL(k_out, dim3(256), dim3(256), 0, stream,
                       embed, ig16_0, ig16_1, ig16_2, user_ids, item_ids, out);
}

// Round 9
// 542.019 us; speedup vs baseline: 1.0553x; 1.0553x over previous
//
#include <hip/hip_runtime.h>
#include <math.h>

#define N_ENT 100000
#define N_USR 50000
#define N_TOT 150000
#define N_ROWS 250000     // unified rows: KG [0,N_ENT) + CF [N_ENT, N_ENT+N_TOT)
#define DD 64

#define SCAN_BLK 256
#define SCAN_ITEMS 1024   // elements per scan block

#define SORT_T 4096       // edges per phase-1 tile
#define BUK_SHIFT 8       // 256 rows per bucket
#define NBUKU 977         // ceil(N_ROWS / 256)
#define LDSCAP 5120       // phase-2 LDS segment capacity (KG bucket mean 3840, std ~62)

typedef _Float16 half8 __attribute__((ext_vector_type(8)));
typedef _Float16 half4 __attribute__((ext_vector_type(4)));
typedef _Float16 h2v __attribute__((ext_vector_type(2)));
typedef float floatx4 __attribute__((ext_vector_type(4)));

// ---------------------------------------------------------------------------
// Per-relation precompute: u_r = Wk_w[0:64]@r, v_r = Wk_w[64:128]@r, c_r = b@r
// uvr layout: [16][132]: u at 0..63, v at 64..127, c at 128
// ---------------------------------------------------------------------------
__global__ void k_rel(const float* __restrict__ Wk_w, const float* __restrict__ Wk_b,
                      const float* __restrict__ rel, float* __restrict__ uvr) {
    int r = blockIdx.x;   // 16 blocks
    int k = threadIdx.x;  // 128 threads
    const float* rv = rel + r * DD;
    const float* wrow = Wk_w + k * DD;
    float s = 0.f;
    for (int j = 0; j < DD; ++j) s += wrow[j] * rv[j];
    uvr[r * 132 + k] = s;
    if (k == 0) {
        float c = 0.f;
        for (int j = 0; j < DD; ++j) c += Wk_b[j] * rv[j];
        uvr[r * 132 + 128] = c;
    }
}

// ---------------------------------------------------------------------------
// Pack U[64][32] into fp16 MFMA B-fragment layout (4 KB). upack lives in the
// HEAD of pairbuf (dead until k_sort_fine) — do not grow the ws tail (round-3
// lesson: OOB past ws_size corrupts adjacent live buffers between phases).
// ---------------------------------------------------------------------------
__global__ void k_uvpack(const float* __restrict__ uvr, _Float16* __restrict__ upack) {
    int i = blockIdx.x * 256 + threadIdx.x;
    if (i >= 2048) return;
    int kstep = i >> 10;
    int rem = i & 1023;
    int ntile = rem >> 9;
    int rem2 = rem & 511;
    int lane = rem2 >> 3;
    int j = rem2 & 7;
    int k = kstep * 32 + (lane >> 4) * 8 + j;
    upack[i] = (_Float16)uvr[(lane & 15) * 132 + ntile * 64 + k];
}

// ---------------------------------------------------------------------------
// Per-entity projections as MFMA GEMM: Puv[100000x32] = e16[100000x64] @ U.
// One wave = 16 rows, 4x mfma_f32_16x16x32_f16 (57us serial-fmaf -> ~8us).
// ---------------------------------------------------------------------------
__global__ __launch_bounds__(256) void k_proj(const _Float16* __restrict__ e16,
        const _Float16* __restrict__ upack, float* __restrict__ Puv) {
    int lane = threadIdx.x & 63;
    int wv = (blockIdx.x * 256 + threadIdx.x) >> 6;
    int row0 = wv * 16;
    if (row0 >= N_ENT) return;
    int m = lane & 15;
    int quad = lane >> 4;

    const _Float16* er = e16 + (size_t)(row0 + m) * DD + quad * 8;
    half8 a0 = *(const half8*)(er);        // k = 0..31 slice
    half8 a1 = *(const half8*)(er + 32);   // k = 32..63 slice

    const half8* up = (const half8*)upack;
    half8 b00 = up[0 * 128 + 0 * 64 + lane];   // kstep0, ntile0
    half8 b01 = up[0 * 128 + 1 * 64 + lane];   // kstep0, ntile1
    half8 b10 = up[1 * 128 + 0 * 64 + lane];   // kstep1, ntile0
    half8 b11 = up[1 * 128 + 1 * 64 + lane];   // kstep1, ntile1

    floatx4 c0 = {0.f, 0.f, 0.f, 0.f};
    floatx4 c1 = {0.f, 0.f, 0.f, 0.f};
    c0 = __builtin_amdgcn_mfma_f32_16x16x32_f16(a0, b00, c0, 0, 0, 0);
    c0 = __builtin_amdgcn_mfma_f32_16x16x32_f16(a1, b10, c0, 0, 0, 0);
    c1 = __builtin_amdgcn_mfma_f32_16x16x32_f16(a0, b01, c1, 0, 0, 0);
    c1 = __builtin_amdgcn_mfma_f32_16x16x32_f16(a1, b11, c1, 0, 0, 0);

    // C/D: row = quad*4 + r, col = ntile*16 + m  [k_gate3-verified layout]
#pragma unroll
    for (int r = 0; r < 4; ++r) {
        size_t row = (size_t)(row0 + quad * 4 + r);
        Puv[row * 32 + m] = c0[r];
        Puv[row * 32 + 16 + m] = c1[r];
    }
}

// ---------------------------------------------------------------------------
// Sort phase 0: per-tile bucket histogram. tilecnt[b * NT + tile] = count.
// ---------------------------------------------------------------------------
__global__ __launch_bounds__(256) void k_sort_hist(const int* __restrict__ kg_h,
        const int* __restrict__ ain_row, int* __restrict__ tilecnt,
        int E_KG, int E_TOT, int NT) {
    __shared__ int hist[1024];
#pragma unroll
    for (int k = 0; k < 4; ++k) hist[k * 256 + threadIdx.x] = 0;
    __syncthreads();
    int tile = blockIdx.x;
    int base = tile * SORT_T;
#pragma unroll
    for (int k = 0; k < SORT_T / 256; ++k) {
        int e = base + k * 256 + threadIdx.x;
        if (e < E_TOT) {
            int row = (e < E_KG) ? kg_h[e] : (N_ENT + ain_row[e - E_KG]);
            atomicAdd(&hist[row >> BUK_SHIFT], 1);
        }
    }
    __syncthreads();
    for (int b = threadIdx.x; b < NBUKU; b += 256)
        tilecnt[b * NT + tile] = hist[b];
}

// --- multi-block exclusive scan, phase 1: per-chunk partial sums ---
__global__ __launch_bounds__(SCAN_BLK) void k_blocksum(const int* __restrict__ cnt,
                                                       int* __restrict__ bsum, int n) {
    __shared__ int s[SCAN_BLK];
    int base = blockIdx.x * SCAN_ITEMS;
    int sum = 0;
    for (int i = threadIdx.x; i < SCAN_ITEMS; i += SCAN_BLK) {
        int idx = base + i;
        if (idx < n) sum += cnt[idx];
    }
    s[threadIdx.x] = sum;
    __syncthreads();
    for (int off = SCAN_BLK / 2; off; off >>= 1) {
        if (threadIdx.x < off) s[threadIdx.x] += s[threadIdx.x + off];
        __syncthreads();
    }
    if (threadIdx.x == 0) bsum[blockIdx.x] = s[0];
}

// --- phase 2: single-block exclusive scan of partials (nb <= 1024) ---
__global__ __launch_bounds__(1024) void k_bscan(int* __restrict__ bsum, int nb,
                                                int* __restrict__ total_out) {
    __shared__ int s[1024];
    int tid = threadIdx.x;
    int v = (tid < nb) ? bsum[tid] : 0;
    s[tid] = v;
    __syncthreads();
    for (int off = 1; off < 1024; off <<= 1) {
        int t = (tid >= off) ? s[tid - off] : 0;
        __syncthreads();
        s[tid] += t;
        __syncthreads();
    }
    if (tid < nb) bsum[tid] = s[tid] - v;   // exclusive
    if (tid == 1023) *total_out = s[1023];
}

// --- phase 3: block-local scan + offset; writes scanned values ---
__global__ __launch_bounds__(SCAN_BLK) void k_scan_apply(const int* __restrict__ cnt,
        int* __restrict__ scanned, const int* __restrict__ bsum, int n) {
    __shared__ int s[SCAN_BLK];
    int base = blockIdx.x * SCAN_ITEMS;
    int t = threadIdx.x;
    int idx0 = base + t * 4;
    int v[4];
    int lsum = 0;
#pragma unroll
    for (int k = 0; k < 4; ++k) {
        int idx = idx0 + k;
        v[k] = (idx < n) ? cnt[idx] : 0;
        lsum += v[k];
    }
    s[t] = lsum;
    __syncthreads();
    for (int off = 1; off < SCAN_BLK; off <<= 1) {
        int tv = (t >= off) ? s[t - off] : 0;
        __syncthreads();
        s[t] += tv;
        __syncthreads();
    }
    int pre = (t ? s[t - 1] : 0) + bsum[blockIdx.x];
#pragma unroll
    for (int k = 0; k < 4; ++k) {
        int idx = idx0 + k;
        if (idx < n) scanned[idx] = pre;
        pre += v[k];
    }
}

// ---------------------------------------------------------------------------
// Sort phase 1: tile-local LDS counting sort, then bucket-run coalesced writes.
// Payload: KG: x = t | r<<17 | rlow<<22, y = junk (filled by fused softmax)
//          CF: x = col | rlow<<22,       y = bits(val)        (rlow = row&255)
// Global slot contract: bucket b's tile-run starts at tilescan[b*NT+tile].
// ---------------------------------------------------------------------------
__global__ __launch_bounds__(256) void k_sort_scatter(const int* __restrict__ kg_h,
        const int* __restrict__ kg_t, const int* __restrict__ kg_r,
        const int* __restrict__ ain_row, const int* __restrict__ ain_col,
        const float* __restrict__ ain_val, const int* __restrict__ tilescan,
        int2* __restrict__ bufA, int E_KG, int E_TOT, int NT) {
    __shared__ int2 seg[SORT_T];      // 32 KB: bucket-sorted payloads
    __shared__ short sbuk[SORT_T];    // 8 KB: bucket id per seg slot
    __shared__ int hist[1024];        // counts -> then gadj = gbase - excl
    __shared__ int cur[1024];         // scatter cursors (start at excl)
    __shared__ int ssum[256];         // scan temp
    int tid = threadIdx.x;
    int tile = blockIdx.x;
#pragma unroll
    for (int k = 0; k < 4; ++k) hist[k * 256 + tid] = 0;
    __syncthreads();

    int base = tile * SORT_T;
    int px[SORT_T / 256], py[SORT_T / 256];
    short pb[SORT_T / 256];
#pragma unroll
    for (int k = 0; k < SORT_T / 256; ++k) {
        int e = base + k * 256 + tid;
        int x = 0, y = 0, b = -1;
        if (e < E_TOT) {
            int row;
            if (e < E_KG) {
                row = kg_h[e];
                x = kg_t[e] | (kg_r[e] << 17) | ((row & 255) << 22);
                y = 0;
            } else {
                int i = e - E_KG;
                row = N_ENT + ain_row[i];
                x = ain_col[i] | ((row & 255) << 22);
                y = __float_as_int(ain_val[i]);
            }
            b = row >> BUK_SHIFT;
            atomicAdd(&hist[b], 1);
        }
        px[k] = x; py[k] = y; pb[k] = (short)b;
    }
    __syncthreads();

    // exclusive scan of hist[0..1023]: thread t owns buckets 4t..4t+3.
    // Afterwards: cur[b] = local excl prefix, hist[b] = gbase[b] - excl[b].
    {
        int b0 = 4 * tid;
        int v0 = hist[b0], v1 = hist[b0 + 1], v2 = hist[b0 + 2], v3 = hist[b0 + 3];
        int g0 = (b0     < NBUKU) ? tilescan[(b0    ) * NT + tile] : 0;
        int g1 = (b0 + 1 < NBUKU) ? tilescan[(b0 + 1) * NT + tile] : 0;
        int g2 = (b0 + 2 < NBUKU) ? tilescan[(b0 + 2) * NT + tile] : 0;
        int g3 = (b0 + 3 < NBUKU) ? tilescan[(b0 + 3) * NT + tile] : 0;
        int lsum = v0 + v1 + v2 + v3;
        ssum[tid] = lsum;
        __syncthreads();
        for (int off = 1; off < 256; off <<= 1) {
            int t = (tid >= off) ? ssum[tid - off] : 0;
            __syncthreads();
            ssum[tid] += t;
            __syncthreads();
        }
        int ex = ssum[tid] - lsum;   // exclusive over thread groups
        cur[b0] = ex;     hist[b0] = g0 - ex;     ex += v0;
        cur[b0 + 1] = ex; hist[b0 + 1] = g1 - ex; ex += v1;
        cur[b0 + 2] = ex; hist[b0 + 2] = g2 - ex; ex += v2;
        cur[b0 + 3] = ex; hist[b0 + 3] = g3 - ex;
    }
    __syncthreads();

    // LDS scatter into bucket-sorted order
#pragma unroll
    for (int k = 0; k < SORT_T / 256; ++k) {
        if (pb[k] >= 0) {
            int slot = atomicAdd(&cur[pb[k]], 1);
            seg[slot] = make_int2(px[k], py[k]);
            sbuk[slot] = pb[k];
        }
    }
    __syncthreads();

    // coalesced write-out: consecutive i in the same bucket -> consecutive
    // global addresses (addr = gbase[b] + (i - excl[b]) = hist[b] + i)
    int cnt = min(SORT_T, E_TOT - base);
    for (int i = tid; i < cnt; i += 256) {
        int b = sbuk[i];
        bufA[hist[b] + i] = seg[i];
    }
}

// ---------------------------------------------------------------------------
// Sort phase 2 + FUSED SEGMENT SOFTMAX. One block per bucket (256 rows).
// rlow-only key (round-6: coltile key was FETCH-neutral, cost +6us).
// ---------------------------------------------------------------------------
__global__ __launch_bounds__(256) void k_sort_fine(const int* __restrict__ tilescan,
        const int2* __restrict__ bufA, int2* __restrict__ pairbuf,
        int* __restrict__ rowptr, const float* __restrict__ Puv,
        const float* __restrict__ uvr, int NT) {
    __shared__ int2 seg[LDSCAP];    // 40 KB
    __shared__ int rcnt[256];
    __shared__ int rexc[256];
    __shared__ int rcur[256];
    __shared__ float rsum[256];
    __shared__ float c16[16];
    int tid = threadIdx.x;
    int b = blockIdx.x;
    rcnt[tid] = 0;
    rsum[tid] = 0.f;
    if (tid < 16) c16[tid] = uvr[tid * 132 + 128];
    __syncthreads();

    int base = tilescan[b * NT];
    int endo = tilescan[(b + 1) * NT];
    int bsize = endo - base;
    int growbase = b << BUK_SHIFT;

    for (int i = base + tid; i < endo; i += 256) {
        unsigned rlow = ((unsigned)bufA[i].x) >> 22;
        atomicAdd(&rcnt[rlow], 1);
    }
    __syncthreads();

    {
        int v = rcnt[tid];
        rexc[tid] = v;
        __syncthreads();
        for (int off = 1; off < 256; off <<= 1) {
            int t = (tid >= off) ? rexc[tid - off] : 0;
            __syncthreads();
            rexc[tid] += t;
            __syncthreads();
        }
        int ex = rexc[tid] - v;     // exclusive
        rexc[tid] = ex;
        rcur[tid] = ex;
        int row = growbase + tid;
        if (row <= N_ROWS) rowptr[row] = base + ex;
    }
    __syncthreads();

    if (bsize <= LDSCAP) {
        for (int i = base + tid; i < endo; i += 256) {
            int2 p = bufA[i];
            unsigned rlow = ((unsigned)p.x) >> 22;
            seg[atomicAdd(&rcur[rlow], 1)] = p;
        }
        __syncthreads();
        for (int i = tid; i < bsize; i += 256) {
            int2 p = seg[i];
            unsigned rlow = ((unsigned)p.x) >> 22;
            int grow = growbase + (int)rlow;
            if (grow < N_ENT) {
                int t = p.x & 0x1FFFF;
                int r = (p.x >> 17) & 15;
                float lg = Puv[(size_t)t * 32 + r] + Puv[(size_t)grow * 32 + 16 + r] + c16[r];
                lg = lg >= 0.f ? lg : 0.01f * lg;
                // softmax is shift-invariant; |logit| << 1 so skip segment-max
                float exv = expf(lg);
                seg[i].y = __float_as_int(exv);
                atomicAdd(&rsum[rlow], exv);
            }
        }
        __syncthreads();
        rsum[tid] = 1.f / rsum[tid];   // unused for CF/empty rows
        __syncthreads();
        for (int i = tid; i < bsize; i += 256) {
            int2 p = seg[i];
            unsigned rlow = ((unsigned)p.x) >> 22;
            if (growbase + (int)rlow < N_ENT)
                p.y = __float_as_int(__int_as_float(p.y) * rsum[rlow]);
            pairbuf[base + i] = p;
        }
    } else {
        for (int i = base + tid; i < endo; i += 256) {
            int2 p = bufA[i];
            unsigned rlow = ((unsigned)p.x) >> 22;
            int slot = atomicAdd(&rcur[rlow], 1);
            pairbuf[base + slot] = p;
        }
        __syncthreads();
        for (int i = base + tid; i < endo; i += 256) {
            int2 p = pairbuf[i];
            unsigned rlow = ((unsigned)p.x) >> 22;
            int grow = growbase + (int)rlow;
            if (grow < N_ENT) {
                int t = p.x & 0x1FFFF;
                int r = (p.x >> 17) & 15;
                float lg = Puv[(size_t)t * 32 + r] + Puv[(size_t)grow * 32 + 16 + r] + c16[r];
                lg = lg >= 0.f ? lg : 0.01f * lg;
                float exv = expf(lg);
                pairbuf[i].y = __float_as_int(exv);
                atomicAdd(&rsum[rlow], exv);
            }
        }
        __syncthreads();
        rsum[tid] = 1.f / rsum[tid];
        __syncthreads();
        for (int i = base + tid; i < endo; i += 256) {
            int2 p = pairbuf[i];
            unsigned rlow = ((unsigned)p.x) >> 22;
            if (growbase + (int)rlow < N_ENT)
                pairbuf[i].y = __float_as_int(__int_as_float(p.y) * rsum[rlow]);
        }
    }
}

// ---------------------------------------------------------------------------
// Pack Wa,Wb into fp16 MFMA B-fragment layout (16 KB).
// ---------------------------------------------------------------------------
__global__ void k_wcvt(const float* __restrict__ Wa, const float* __restrict__ Wb,
                       _Float16* __restrict__ wpack) {
    int i = blockIdx.x * 256 + threadIdx.x;
    if (i >= 8192) return;
    int m = i >> 12;
    int rem = i & 4095;
    int kstep = rem >> 11;
    int rem2 = rem & 2047;
    int ntile = rem2 >> 9;
    int rem3 = rem2 & 511;
    int lane = rem3 >> 3;
    int j = rem3 & 7;
    int k = kstep * 32 + (lane >> 4) * 8 + j;
    int n = ntile * 16 + (lane & 15);
    const float* W = m ? Wb : Wa;
    wpack[i] = (_Float16)W[k * 64 + n];
}

// ---------------------------------------------------------------------------
// MERGED PAIRED-ROW CSR SpMM v3. Round-8 post-mortem: v2's nontemporal
// pairbuf loads bypassed L2 and broke the 8-entries-per-64B-line spatial
// reuse -> FETCH +23MB (~= pairbuf size), dur 98->108us. v3 keeps the
// unroll-8 MLP lever (8 independent gathers in flight/wave-half) but
// restores plain cached pairbuf loads. Isolates the MLP hypothesis:
// round-7 showed BW responds to concurrency (3.33->3.54 TB/s on merge).
// ---------------------------------------------------------------------------
__global__ __launch_bounds__(256) void k_spmm2(const int* __restrict__ rowptr,
        const int2* __restrict__ pairbuf, const _Float16* __restrict__ xkg,
        const _Float16* __restrict__ xcf, _Float16* __restrict__ outkg,
        _Float16* __restrict__ outcf, int row_begin) {
    int wid0 = (blockIdx.x * 256 + threadIdx.x) >> 6;
    int wpair = __builtin_amdgcn_readfirstlane(wid0);
    int lane = threadIdx.x & 63;
    int half = lane >> 5;
    int sub = lane & 31;
    int row = row_begin + wpair * 2 + half;
    if (row >= N_ROWS) return;
    int d0 = sub * 2;
    bool kg = row < N_ENT;
    const _Float16* xb = (kg ? xkg : xcf) + d0;
    int cmask = kg ? 0x1FFFF : 0x3FFFF;
    _Float16* ob = kg ? (outkg + (size_t)row * DD)
                      : (outcf + (size_t)(row - N_ENT) * DD);
    int s = rowptr[row], e = rowptr[row + 1];
    float a00 = 0.f, a01 = 0.f, a10 = 0.f, a11 = 0.f;
    float a20 = 0.f, a21 = 0.f, a30 = 0.f, a31 = 0.f;
    float a40 = 0.f, a41 = 0.f, a50 = 0.f, a51 = 0.f;
    float a60 = 0.f, a61 = 0.f, a70 = 0.f, a71 = 0.f;
    int i = s;
    for (; i + 8 <= e; i += 8) {
        int2 p0 = pairbuf[i],     p1 = pairbuf[i + 1];
        int2 p2 = pairbuf[i + 2], p3 = pairbuf[i + 3];
        int2 p4 = pairbuf[i + 4], p5 = pairbuf[i + 5];
        int2 p6 = pairbuf[i + 6], p7 = pairbuf[i + 7];
        h2v g0 = *(const h2v*)(xb + (size_t)(p0.x & cmask) * DD);
        h2v g1 = *(const h2v*)(xb + (size_t)(p1.x & cmask) * DD);
        h2v g2 = *(const h2v*)(xb + (size_t)(p2.x & cmask) * DD);
        h2v g3 = *(const h2v*)(xb + (size_t)(p3.x & cmask) * DD);
        h2v g4 = *(const h2v*)(xb + (size_t)(p4.x & cmask) * DD);
        h2v g5 = *(const h2v*)(xb + (size_t)(p5.x & cmask) * DD);
        h2v g6 = *(const h2v*)(xb + (size_t)(p6.x & cmask) * DD);
        h2v g7 = *(const h2v*)(xb + (size_t)(p7.x & cmask) * DD);
        float w0 = __int_as_float(p0.y), w1 = __int_as_float(p1.y);
        float w2 = __int_as_float(p2.y), w3 = __int_as_float(p3.y);
        float w4 = __int_as_float(p4.y), w5 = __int_as_float(p5.y);
        float w6 = __int_as_float(p6.y), w7 = __int_as_float(p7.y);
        a00 = fmaf(w0, (float)g0[0], a00); a01 = fmaf(w0, (float)g0[1], a01);
        a10 = fmaf(w1, (float)g1[0], a10); a11 = fmaf(w1, (float)g1[1], a11);
        a20 = fmaf(w2, (float)g2[0], a20); a21 = fmaf(w2, (float)g2[1], a21);
        a30 = fmaf(w3, (float)g3[0], a30); a31 = fmaf(w3, (float)g3[1], a31);
        a40 = fmaf(w4, (float)g4[0], a40); a41 = fmaf(w4, (float)g4[1], a41);
        a50 = fmaf(w5, (float)g5[0], a50); a51 = fmaf(w5, (float)g5[1], a51);
        a60 = fmaf(w6, (float)g6[0], a60); a61 = fmaf(w6, (float)g6[1], a61);
        a70 = fmaf(w7, (float)g7[0], a70); a71 = fmaf(w7, (float)g7[1], a71);
    }
    for (; i + 2 <= e; i += 2) {
        int2 p0 = pairbuf[i], p1 = pairbuf[i + 1];
        h2v g0 = *(const h2v*)(xb + (size_t)(p0.x & cmask) * DD);
        h2v g1 = *(const h2v*)(xb + (size_t)(p1.x & cmask) * DD);
        float w0 = __int_as_float(p0.y), w1 = __int_as_float(p1.y);
        a00 = fmaf(w0, (float)g0[0], a00); a01 = fmaf(w0, (float)g0[1], a01);
        a10 = fmaf(w1, (float)g1[0], a10); a11 = fmaf(w1, (float)g1[1], a11);
    }
    if (i < e) {
        int2 p0 = pairbuf[i];
        h2v g0 = *(const h2v*)(xb + (size_t)(p0.x & cmask) * DD);
        float w0 = __int_as_float(p0.y);
        a00 = fmaf(w0, (float)g0[0], a00); a01 = fmaf(w0, (float)g0[1], a01);
    }
    float r0 = ((a00 + a10) + (a20 + a30)) + ((a40 + a50) + (a60 + a70));
    float r1 = ((a01 + a11) + (a21 + a31)) + ((a41 + a51) + (a61 + a71));
    h2v st; st[0] = (_Float16)r0; st[1] = (_Float16)r1;
    *(h2v*)(ob + d0) = st;
}

// ---------------------------------------------------------------------------
// Entity gate via MFMA (one wave = 16 rows), FUSED with user passthrough copy:
// blocks >= ngate copy ig16 user rows into dual16 (half8).
// acc = kg@Wa + ig@Wb in one accumulator chain.
// C/D: col=lane&15, row=(lane>>4)*4+reg [m89-verified].
// ---------------------------------------------------------------------------
__global__ __launch_bounds__(256) void k_gate3(const _Float16* __restrict__ kg16,
        const _Float16* __restrict__ ig16, const _Float16* __restrict__ wpack,
        _Float16* __restrict__ dual16, int ngate) {
    __shared__ _Float16 sw[8192];
    if ((int)blockIdx.x >= ngate) {
        int i = ((int)blockIdx.x - ngate) * 256 + threadIdx.x;
        if (i < N_USR * DD / 8) {
            size_t o = (size_t)N_ENT * DD / 8 + i;
            ((half8*)dual16)[o] = ((const half8*)ig16)[o];
        }
        return;
    }
    for (int i = threadIdx.x * 8; i < 8192; i += 256 * 8)
        *(half8*)(sw + i) = *(const half8*)(wpack + i);
    __syncthreads();
    int lane = threadIdx.x & 63;
    int wv = (blockIdx.x * 256 + threadIdx.x) >> 6;
    int row0 = wv * 16;
    if (row0 >= N_ENT) return;
    int m = lane & 15;
    int quad = lane >> 4;

    const _Float16* kgr = kg16 + (size_t)(row0 + m) * DD + quad * 8;
    const _Float16* igr = ig16 + (size_t)(row0 + m) * DD + quad * 8;
    half8 akg0 = *(const half8*)(kgr);
    half8 akg1 = *(const half8*)(kgr + 32);
    half8 aig0 = *(const half8*)(igr);
    half8 aig1 = *(const half8*)(igr + 32);

    floatx4 acc[4];
#pragma unroll
    for (int t = 0; t < 4; ++t) {
        half8 bA0 = *(const half8*)(sw + 0 * 4096 + 0 * 2048 + t * 512 + lane * 8);
        half8 bA1 = *(const half8*)(sw + 0 * 4096 + 1 * 2048 + t * 512 + lane * 8);
        half8 bB0 = *(const half8*)(sw + 1 * 4096 + 0 * 2048 + t * 512 + lane * 8);
        half8 bB1 = *(const half8*)(sw + 1 * 4096 + 1 * 2048 + t * 512 + lane * 8);
        floatx4 c = {0.f, 0.f, 0.f, 0.f};
        c = __builtin_amdgcn_mfma_f32_16x16x32_f16(akg0, bA0, c, 0, 0, 0);
        c = __builtin_amdgcn_mfma_f32_16x16x32_f16(akg1, bA1, c, 0, 0, 0);
        c = __builtin_amdgcn_mfma_f32_16x16x32_f16(aig0, bB0, c, 0, 0, 0);
        c = __builtin_amdgcn_mfma_f32_16x16x32_f16(aig1, bB1, c, 0, 0, 0);
        acc[t] = c;
    }

#pragma unroll
    for (int t = 0; t < 4; ++t) {
#pragma unroll
        for (int r = 0; r < 4; ++r) {
            int row = quad * 4 + r;
            int col = t * 16 + m;
            size_t o = (size_t)(row0 + row) * DD + col;
            float kv = (float)kg16[o];
            float cv = (float)ig16[o];
            float g = 1.f / (1.f + expf(-acc[t][r]));
            dual16[o] = (_Float16)(g * kv + (1.f - g) * cv);
        }
    }
}

// init: dual16 = fp16(embed)
__global__ void k_init(const float* __restrict__ embed, _Float16* __restrict__ dual16) {
    int i = blockIdx.x * blockDim.x + threadIdx.x;
    if (i >= N_TOT * DD) return;
    dual16[i] = (_Float16)embed[i];
}

// ---------------------------------------------------------------------------
// out[u,j] = sums[user_ids[u]] . sums[item_ids[j]],
// sums[row] = embed[row] + ig0[row] + ig1[row] + ig2[row] (reconstructed).
// 256 blocks: 32 user-groups (32 users) x 8 item-chunks (256 items).
// ---------------------------------------------------------------------------
__global__ __launch_bounds__(256) void k_out(const float* __restrict__ embed,
        const _Float16* __restrict__ ig0, const _Float16* __restrict__ ig1,
        const _Float16* __restrict__ ig2, const int* __restrict__ user_ids,
        const int* __restrict__ item_ids, float* __restrict__ out) {
    __shared__ float uvec[32 * DD];
    int ug = blockIdx.x >> 3;
    int qi = blockIdx.x & 7;
    int ub = ug * 32;
    for (int i = threadIdx.x; i < 32 * DD; i += 256) {
        int uu = i >> 6, d = i & 63;
        size_t o = (size_t)user_ids[ub + uu] * DD + d;
        uvec[i] = embed[o] + (float)ig0[o] + (float)ig1[o] + (float)ig2[o];
    }
    __syncthreads();
    int jbase = qi * 256;
    for (int j = threadIdx.x; j < 256; j += 256) {
        size_t ro = (size_t)item_ids[jbase + j] * DD;
        float acc[32];
#pragma unroll
        for (int u = 0; u < 32; ++u) acc[u] = 0.f;
        for (int d = 0; d < DD; d += 4) {
            float4 ev = *(const float4*)(embed + ro + d);
            half4 h0 = *(const half4*)(ig0 + ro + d);
            half4 h1 = *(const half4*)(ig1 + ro + d);
            half4 h2 = *(const half4*)(ig2 + ro + d);
            float iv0 = ev.x + (float)h0[0] + (float)h1[0] + (float)h2[0];
            float iv1 = ev.y + (float)h0[1] + (float)h1[1] + (float)h2[1];
            float iv2 = ev.z + (float)h0[2] + (float)h1[2] + (float)h2[2];
            float iv3 = ev.w + (float)h0[3] + (float)h1[3] + (float)h2[3];
#pragma unroll
            for (int u = 0; u < 32; ++u) {
                acc[u] = fmaf(iv0, uvec[u * DD + d + 0], acc[u]);
                acc[u] = fmaf(iv1, uvec[u * DD + d + 1], acc[u]);
                acc[u] = fmaf(iv2, uvec[u * DD + d + 2], acc[u]);
                acc[u] = fmaf(iv3, uvec[u * DD + d + 3], acc[u]);
            }
        }
#pragma unroll
        for (int u = 0; u < 32; ++u)
            out[(size_t)(ub + u) * 2048 + jbase + j] = acc[u];
    }
}

extern "C" void kernel_launch(void* const* d_in, const int* in_sizes, int n_in,
                              void* d_out, int out_size, void* d_ws, size_t ws_size,
                              hipStream_t stream) {
    const float* embed   = (const float*)d_in[0];
    const float* rel     = (const float*)d_in[1];
    const float* Wk_w    = (const float*)d_in[2];
    const float* Wk_b    = (const float*)d_in[3];
    const float* Wa      = (const float*)d_in[4];
    const float* Wb      = (const float*)d_in[5];
    const int*   kg_h    = (const int*)d_in[6];
    const int*   kg_t    = (const int*)d_in[7];
    const int*   kg_r    = (const int*)d_in[8];
    const int*   ain_row = (const int*)d_in[9];
    const int*   ain_col = (const int*)d_in[10];
    const float* ain_val = (const float*)d_in[11];
    const int*   user_ids = (const int*)d_in[12];
    const int*   item_ids = (const int*)d_in[13];
    int E_KG = in_sizes[6];
    int E_CF = in_sizes[9];
    int E_TOT = E_KG + E_CF;
    float* out = (float*)d_out;

    int NT  = (E_TOT + SORT_T - 1) / SORT_T;   // phase-1 tiles (733)
    int NTC = NBUKU * NT;                       // scan length (~716K)

    float* ws = (float*)d_ws;
    size_t off = 0;
    float* uvr       = ws + off; off += 16 * 132;
    float* Puv       = ws + off; off += (size_t)N_ENT * 32;
    int*   rowptr    = (int*)(ws + off); off += N_ROWS + 4;
    int*   tilecnt   = (int*)(ws + off); off += (size_t)NTC + 4;
    int*   tilescan  = (int*)(ws + off); off += (size_t)NTC + 4;
    int*   bsum      = (int*)(ws + off); off += 1024;
    int2*  pairbuf   = (int2*)(ws + off); off += 2 * (size_t)E_TOT;   // final (row-sorted)
    _Float16* dual16 = (_Float16*)(ws + off); off += (size_t)N_TOT * DD / 2;
    _Float16* ig16_0 = (_Float16*)(ws + off); off += (size_t)N_TOT * DD / 2;
    _Float16* ig16_1 = (_Float16*)(ws + off); off += (size_t)N_TOT * DD / 2;
    _Float16* ig16_2 = (_Float16*)(ws + off); off += (size_t)N_TOT * DD / 2;
    _Float16* kg16A  = (_Float16*)(ws + off); off += (size_t)N_ENT * DD / 2;
    _Float16* kg16B  = (_Float16*)(ws + off); off += (size_t)N_ENT * DD / 2;
    _Float16* wpack  = (_Float16*)(ws + off); off += 8192 / 2;
    int2*  bufA      = (int2*)kg16A;   // alias: 24MB <= kg16A+kg16B (25.6MB); dead before layer0
    // upack aliases the HEAD of pairbuf (4 KB): written by k_uvpack, read by
    // k_proj, both strictly before k_sort_fine first writes pairbuf. Keeps the
    // ws footprint identical to the harness-verified round-0/1 layout (no tail
    // growth -> no OOB past ws_size).
    _Float16* upack  = (_Float16*)pairbuf;
    _Float16* ig_l[3] = {ig16_0, ig16_1, ig16_2};

    // --- attention precompute (needed by fused sort+softmax) ---
    // k_init first: dual16 (fp16 embed) feeds the MFMA k_proj.
    hipLaunchKernelGGL(k_init, dim3((N_TOT * DD + 255) / 256), dim3(256), 0, stream,
                       embed, dual16);
    hipLaunchKernelGGL(k_rel, dim3(16), dim3(128), 0, stream, Wk_w, Wk_b, rel, uvr);
    hipLaunchKernelGGL(k_uvpack, dim3(8), dim3(256), 0, stream, uvr, upack);
    hipLaunchKernelGGL(k_proj, dim3((N_ENT / 16 + 3) / 4), dim3(256), 0, stream,
                       dual16, upack, Puv);

    // --- binning sort: hist -> scan -> tile scatter -> fine sort + softmax ---
    hipLaunchKernelGGL(k_sort_hist, dim3(NT), dim3(256), 0, stream,
                       kg_h, ain_row, tilecnt, E_KG, E_TOT, NT);
    int nb = (NTC + SCAN_ITEMS - 1) / SCAN_ITEMS;   // ~700
    hipLaunchKernelGGL(k_blocksum, dim3(nb), dim3(SCAN_BLK), 0, stream, tilecnt, bsum, NTC);
    hipLaunchKernelGGL(k_bscan, dim3(1), dim3(1024), 0, stream, bsum, nb, tilescan + NTC);
    hipLaunchKernelGGL(k_scan_apply, dim3(nb), dim3(SCAN_BLK), 0, stream,
                       tilecnt, tilescan, bsum, NTC);
    hipLaunchKernelGGL(k_sort_scatter, dim3(NT), dim3(256), 0, stream,
                       kg_h, kg_t, kg_r, ain_row, ain_col, ain_val, tilescan,
                       bufA, E_KG, E_TOT, NT);
    hipLaunchKernelGGL(k_sort_fine, dim3(NBUKU), dim3(256), 0, stream,
                       tilescan, bufA, pairbuf, rowptr, Puv, uvr, NT);

    hipLaunchKernelGGL(k_wcvt, dim3(32), dim3(256), 0, stream, Wa, Wb, wpack);

    // --- 3 propagation layers; layers 0/1 use the MERGED KG+CF spmm ---
    const _Float16* cur16 = dual16;       // layer0 KG gather table = fp16 embed
    _Float16* kg16o = kg16A;
    _Float16* kg16alt = kg16B;
    int all_blocks = ((N_ROWS / 2) * 64 + 255) / 256;   // 31250
    int cf_blocks = ((N_TOT / 2) * 64 + 255) / 256;     // 18750
    int ngate = (N_ENT / 16 + 3) / 4;                   // 1563
    int nuc = (N_USR * DD / 8 + 255) / 256;             // 1563
    for (int layer = 0; layer < 3; ++layer) {
        if (layer < 2) {
            hipLaunchKernelGGL(k_spmm2, dim3(all_blocks), dim3(256), 0, stream,
                               rowptr, pairbuf, cur16, dual16, kg16o, ig_l[layer], 0);
            hipLaunchKernelGGL(k_gate3, dim3(ngate + nuc), dim3(256), 0, stream,
                               kg16o, ig_l[layer], wpack, dual16, ngate);
            cur16 = kg16o;
            kg16o = kg16alt;
            kg16alt = (_Float16*)cur16;
        } else {
            hipLaunchKernelGGL(k_spmm2, dim3(cf_blocks), dim3(256), 0, stream,
                               rowptr, pairbuf, dual16, dual16, kg16o, ig_l[layer], N_ENT);
        }
    }

    // --- final gather-GEMM 1024 x 2048 x 64 with on-the-fly sums ---
    hipLaunchKernelGGL(k_out, dim3(256), dim3(256), 0, stream,
                       embed, ig16_0, ig16_1, ig16_2, user_ids, item_ids, out);
}

// Round 10
// 536.740 us; speedup vs baseline: 1.0657x; 1.0098x over previous
//
#include <hip/hip_runtime.h>
#include <math.h>

#define N_ENT 100000
#define N_USR 50000
#define N_TOT 150000
#define N_ROWS 250000     // unified rows: KG [0,N_ENT) + CF [N_ENT, N_ENT+N_TOT)
#define DD 64

#define SCAN_BLK 256
#define SCAN_ITEMS 1024   // elements per scan block

#define SORT_T 4096       // edges per phase-1 tile
#define BUK_SHIFT 8       // 256 rows per bucket
#define NBUKU 977         // ceil(N_ROWS / 256)
#define LDSCAP 5120       // phase-2 LDS segment capacity (KG bucket mean 3840, std ~62)

typedef _Float16 half8 __attribute__((ext_vector_type(8)));
typedef _Float16 half4 __attribute__((ext_vector_type(4)));
typedef _Float16 h2v __attribute__((ext_vector_type(2)));
typedef float floatx4 __attribute__((ext_vector_type(4)));

// ---------------------------------------------------------------------------
// Per-relation precompute: u_r = Wk_w[0:64]@r, v_r = Wk_w[64:128]@r, c_r = b@r
// uvr layout: [16][132]: u at 0..63, v at 64..127, c at 128
// ---------------------------------------------------------------------------
__global__ void k_rel(const float* __restrict__ Wk_w, const float* __restrict__ Wk_b,
                      const float* __restrict__ rel, float* __restrict__ uvr) {
    int r = blockIdx.x;   // 16 blocks
    int k = threadIdx.x;  // 128 threads
    const float* rv = rel + r * DD;
    const float* wrow = Wk_w + k * DD;
    float s = 0.f;
    for (int j = 0; j < DD; ++j) s += wrow[j] * rv[j];
    uvr[r * 132 + k] = s;
    if (k == 0) {
        float c = 0.f;
        for (int j = 0; j < DD; ++j) c += Wk_b[j] * rv[j];
        uvr[r * 132 + 128] = c;
    }
}

// ---------------------------------------------------------------------------
// Pack U[64][32] into fp16 MFMA B-fragment layout (4 KB). upack lives in the
// HEAD of pairbuf (dead until k_sort_fine) — do not grow the ws tail (round-3
// lesson: OOB past ws_size corrupts adjacent live buffers between phases).
// ---------------------------------------------------------------------------
__global__ void k_uvpack(const float* __restrict__ uvr, _Float16* __restrict__ upack) {
    int i = blockIdx.x * 256 + threadIdx.x;
    if (i >= 2048) return;
    int kstep = i >> 10;
    int rem = i & 1023;
    int ntile = rem >> 9;
    int rem2 = rem & 511;
    int lane = rem2 >> 3;
    int j = rem2 & 7;
    int k = kstep * 32 + (lane >> 4) * 8 + j;
    upack[i] = (_Float16)uvr[(lane & 15) * 132 + ntile * 64 + k];
}

// ---------------------------------------------------------------------------
// Per-entity projections as MFMA GEMM, SPLIT OUTPUT (round-9):
//   Pu16[N_ENT][16] fp16 (3.2MB)  — t-side, gathered RANDOMLY by k_sort_fine.
//     Old interleaved [row][32] fp32 spread the u-values over a 6.4MB window
//     (> 4MB XCD L2 -> thrash, 64B line per 4B access). 3.2MB is L2-resident.
//   Pv32[N_ENT][16] fp32 (6.4MB)  — row-side, read in 16KB/bucket windows.
// fp16 on u: |P|~0.1-0.5, rel err 5e-4 -> logit err ~1e-4, cancels in softmax.
// ---------------------------------------------------------------------------
__global__ __launch_bounds__(256) void k_proj(const _Float16* __restrict__ e16,
        const _Float16* __restrict__ upack, _Float16* __restrict__ Pu16,
        float* __restrict__ Pv32) {
    int lane = threadIdx.x & 63;
    int wv = (blockIdx.x * 256 + threadIdx.x) >> 6;
    int row0 = wv * 16;
    if (row0 >= N_ENT) return;
    int m = lane & 15;
    int quad = lane >> 4;

    const _Float16* er = e16 + (size_t)(row0 + m) * DD + quad * 8;
    half8 a0 = *(const half8*)(er);        // k = 0..31 slice
    half8 a1 = *(const half8*)(er + 32);   // k = 32..63 slice

    const half8* up = (const half8*)upack;
    half8 b00 = up[0 * 128 + 0 * 64 + lane];   // kstep0, ntile0 (u)
    half8 b01 = up[0 * 128 + 1 * 64 + lane];   // kstep0, ntile1 (v)
    half8 b10 = up[1 * 128 + 0 * 64 + lane];   // kstep1, ntile0
    half8 b11 = up[1 * 128 + 1 * 64 + lane];   // kstep1, ntile1

    floatx4 c0 = {0.f, 0.f, 0.f, 0.f};
    floatx4 c1 = {0.f, 0.f, 0.f, 0.f};
    c0 = __builtin_amdgcn_mfma_f32_16x16x32_f16(a0, b00, c0, 0, 0, 0);
    c0 = __builtin_amdgcn_mfma_f32_16x16x32_f16(a1, b10, c0, 0, 0, 0);
    c1 = __builtin_amdgcn_mfma_f32_16x16x32_f16(a0, b01, c1, 0, 0, 0);
    c1 = __builtin_amdgcn_mfma_f32_16x16x32_f16(a1, b11, c1, 0, 0, 0);

    // C/D: row = quad*4 + r, col = ntile*16 + m  [k_gate3-verified layout]
#pragma unroll
    for (int r = 0; r < 4; ++r) {
        size_t row = (size_t)(row0 + quad * 4 + r);
        Pu16[row * 16 + m] = (_Float16)c0[r];
        Pv32[row * 16 + m] = c1[r];
    }
}

// ---------------------------------------------------------------------------
// Sort phase 0: per-tile bucket histogram. tilecnt[b * NT + tile] = count.
// ---------------------------------------------------------------------------
__global__ __launch_bounds__(256) void k_sort_hist(const int* __restrict__ kg_h,
        const int* __restrict__ ain_row, int* __restrict__ tilecnt,
        int E_KG, int E_TOT, int NT) {
    __shared__ int hist[1024];
#pragma unroll
    for (int k = 0; k < 4; ++k) hist[k * 256 + threadIdx.x] = 0;
    __syncthreads();
    int tile = blockIdx.x;
    int base = tile * SORT_T;
#pragma unroll
    for (int k = 0; k < SORT_T / 256; ++k) {
        int e = base + k * 256 + threadIdx.x;
        if (e < E_TOT) {
            int row = (e < E_KG) ? kg_h[e] : (N_ENT + ain_row[e - E_KG]);
            atomicAdd(&hist[row >> BUK_SHIFT], 1);
        }
    }
    __syncthreads();
    for (int b = threadIdx.x; b < NBUKU; b += 256)
        tilecnt[b * NT + tile] = hist[b];
}

// --- multi-block exclusive scan, phase 1: per-chunk partial sums ---
__global__ __launch_bounds__(SCAN_BLK) void k_blocksum(const int* __restrict__ cnt,
                                                       int* __restrict__ bsum, int n) {
    __shared__ int s[SCAN_BLK];
    int base = blockIdx.x * SCAN_ITEMS;
    int sum = 0;
    for (int i = threadIdx.x; i < SCAN_ITEMS; i += SCAN_BLK) {
        int idx = base + i;
        if (idx < n) sum += cnt[idx];
    }
    s[threadIdx.x] = sum;
    __syncthreads();
    for (int off = SCAN_BLK / 2; off; off >>= 1) {
        if (threadIdx.x < off) s[threadIdx.x] += s[threadIdx.x + off];
        __syncthreads();
    }
    if (threadIdx.x == 0) bsum[blockIdx.x] = s[0];
}

// --- phase 2: single-block exclusive scan of partials (nb <= 1024) ---
__global__ __launch_bounds__(1024) void k_bscan(int* __restrict__ bsum, int nb,
                                                int* __restrict__ total_out) {
    __shared__ int s[1024];
    int tid = threadIdx.x;
    int v = (tid < nb) ? bsum[tid] : 0;
    s[tid] = v;
    __syncthreads();
    for (int off = 1; off < 1024; off <<= 1) {
        int t = (tid >= off) ? s[tid - off] : 0;
        __syncthreads();
        s[tid] += t;
        __syncthreads();
    }
    if (tid < nb) bsum[tid] = s[tid] - v;   // exclusive
    if (tid == 1023) *total_out = s[1023];
}

// --- phase 3: block-local scan + offset; writes scanned values ---
__global__ __launch_bounds__(SCAN_BLK) void k_scan_apply(const int* __restrict__ cnt,
        int* __restrict__ scanned, const int* __restrict__ bsum, int n) {
    __shared__ int s[SCAN_BLK];
    int base = blockIdx.x * SCAN_ITEMS;
    int t = threadIdx.x;
    int idx0 = base + t * 4;
    int v[4];
    int lsum = 0;
#pragma unroll
    for (int k = 0; k < 4; ++k) {
        int idx = idx0 + k;
        v[k] = (idx < n) ? cnt[idx] : 0;
        lsum += v[k];
    }
    s[t] = lsum;
    __syncthreads();
    for (int off = 1; off < SCAN_BLK; off <<= 1) {
        int tv = (t >= off) ? s[t - off] : 0;
        __syncthreads();
        s[t] += tv;
        __syncthreads();
    }
    int pre = (t ? s[t - 1] : 0) + bsum[blockIdx.x];
#pragma unroll
    for (int k = 0; k < 4; ++k) {
        int idx = idx0 + k;
        if (idx < n) scanned[idx] = pre;
        pre += v[k];
    }
}

// ---------------------------------------------------------------------------
// Sort phase 1: tile-local LDS counting sort, then bucket-run coalesced writes.
// Payload: KG: x = t | r<<17 | rlow<<22, y = junk (filled by fused softmax)
//          CF: x = col | rlow<<22,       y = bits(val)        (rlow = row&255)
// Global slot contract: bucket b's tile-run starts at tilescan[b*NT+tile].
// ---------------------------------------------------------------------------
__global__ __launch_bounds__(256) void k_sort_scatter(const int* __restrict__ kg_h,
        const int* __restrict__ kg_t, const int* __restrict__ kg_r,
        const int* __restrict__ ain_row, const int* __restrict__ ain_col,
        const float* __restrict__ ain_val, const int* __restrict__ tilescan,
        int2* __restrict__ bufA, int E_KG, int E_TOT, int NT) {
    __shared__ int2 seg[SORT_T];      // 32 KB: bucket-sorted payloads
    __shared__ short sbuk[SORT_T];    // 8 KB: bucket id per seg slot
    __shared__ int hist[1024];        // counts -> then gadj = gbase - excl
    __shared__ int cur[1024];         // scatter cursors (start at excl)
    __shared__ int ssum[256];         // scan temp
    int tid = threadIdx.x;
    int tile = blockIdx.x;
#pragma unroll
    for (int k = 0; k < 4; ++k) hist[k * 256 + tid] = 0;
    __syncthreads();

    int base = tile * SORT_T;
    int px[SORT_T / 256], py[SORT_T / 256];
    short pb[SORT_T / 256];
#pragma unroll
    for (int k = 0; k < SORT_T / 256; ++k) {
        int e = base + k * 256 + tid;
        int x = 0, y = 0, b = -1;
        if (e < E_TOT) {
            int row;
            if (e < E_KG) {
                row = kg_h[e];
                x = kg_t[e] | (kg_r[e] << 17) | ((row & 255) << 22);
                y = 0;
            } else {
                int i = e - E_KG;
                row = N_ENT + ain_row[i];
                x = ain_col[i] | ((row & 255) << 22);
                y = __float_as_int(ain_val[i]);
            }
            b = row >> BUK_SHIFT;
            atomicAdd(&hist[b], 1);
        }
        px[k] = x; py[k] = y; pb[k] = (short)b;
    }
    __syncthreads();

    // exclusive scan of hist[0..1023]: thread t owns buckets 4t..4t+3.
    // Afterwards: cur[b] = local excl prefix, hist[b] = gbase[b] - excl[b].
    {
        int b0 = 4 * tid;
        int v0 = hist[b0], v1 = hist[b0 + 1], v2 = hist[b0 + 2], v3 = hist[b0 + 3];
        int g0 = (b0     < NBUKU) ? tilescan[(b0    ) * NT + tile] : 0;
        int g1 = (b0 + 1 < NBUKU) ? tilescan[(b0 + 1) * NT + tile] : 0;
        int g2 = (b0 + 2 < NBUKU) ? tilescan[(b0 + 2) * NT + tile] : 0;
        int g3 = (b0 + 3 < NBUKU) ? tilescan[(b0 + 3) * NT + tile] : 0;
        int lsum = v0 + v1 + v2 + v3;
        ssum[tid] = lsum;
        __syncthreads();
        for (int off = 1; off < 256; off <<= 1) {
            int t = (tid >= off) ? ssum[tid - off] : 0;
            __syncthreads();
            ssum[tid] += t;
            __syncthreads();
        }
        int ex = ssum[tid] - lsum;   // exclusive over thread groups
        cur[b0] = ex;     hist[b0] = g0 - ex;     ex += v0;
        cur[b0 + 1] = ex; hist[b0 + 1] = g1 - ex; ex += v1;
        cur[b0 + 2] = ex; hist[b0 + 2] = g2 - ex; ex += v2;
        cur[b0 + 3] = ex; hist[b0 + 3] = g3 - ex;
    }
    __syncthreads();

    // LDS scatter into bucket-sorted order
#pragma unroll
    for (int k = 0; k < SORT_T / 256; ++k) {
        if (pb[k] >= 0) {
            int slot = atomicAdd(&cur[pb[k]], 1);
            seg[slot] = make_int2(px[k], py[k]);
            sbuk[slot] = pb[k];
        }
    }
    __syncthreads();

    // coalesced write-out: consecutive i in the same bucket -> consecutive
    // global addresses (addr = gbase[b] + (i - excl[b]) = hist[b] + i)
    int cnt = min(SORT_T, E_TOT - base);
    for (int i = tid; i < cnt; i += 256) {
        int b = sbuk[i];
        bufA[hist[b] + i] = seg[i];
    }
}

// ---------------------------------------------------------------------------
// Sort phase 2 + FUSED SEGMENT SOFTMAX. One block per bucket (256 rows).
// rlow-only key (round-6: coltile key was FETCH-neutral, cost +6us).
// Round-9: logits read split tables Pu16 (fp16, L2-resident 3.2MB, random
// t-side) + Pv32 (fp32, 16KB/bucket row-side window).
// ---------------------------------------------------------------------------
__global__ __launch_bounds__(256) void k_sort_fine(const int* __restrict__ tilescan,
        const int2* __restrict__ bufA, int2* __restrict__ pairbuf,
        int* __restrict__ rowptr, const _Float16* __restrict__ Pu16,
        const float* __restrict__ Pv32, const float* __restrict__ uvr, int NT) {
    __shared__ int2 seg[LDSCAP];    // 40 KB
    __shared__ int rcnt[256];
    __shared__ int rexc[256];
    __shared__ int rcur[256];
    __shared__ float rsum[256];
    __shared__ float c16[16];
    int tid = threadIdx.x;
    int b = blockIdx.x;
    rcnt[tid] = 0;
    rsum[tid] = 0.f;
    if (tid < 16) c16[tid] = uvr[tid * 132 + 128];
    __syncthreads();

    int base = tilescan[b * NT];
    int endo = tilescan[(b + 1) * NT];
    int bsize = endo - base;
    int growbase = b << BUK_SHIFT;

    for (int i = base + tid; i < endo; i += 256) {
        unsigned rlow = ((unsigned)bufA[i].x) >> 22;
        atomicAdd(&rcnt[rlow], 1);
    }
    __syncthreads();

    {
        int v = rcnt[tid];
        rexc[tid] = v;
        __syncthreads();
        for (int off = 1; off < 256; off <<= 1) {
            int t = (tid >= off) ? rexc[tid - off] : 0;
            __syncthreads();
            rexc[tid] += t;
            __syncthreads();
        }
        int ex = rexc[tid] - v;     // exclusive
        rexc[tid] = ex;
        rcur[tid] = ex;
        int row = growbase + tid;
        if (row <= N_ROWS) rowptr[row] = base + ex;
    }
    __syncthreads();

    if (bsize <= LDSCAP) {
        for (int i = base + tid; i < endo; i += 256) {
            int2 p = bufA[i];
            unsigned rlow = ((unsigned)p.x) >> 22;
            seg[atomicAdd(&rcur[rlow], 1)] = p;
        }
        __syncthreads();
        for (int i = tid; i < bsize; i += 256) {
            int2 p = seg[i];
            unsigned rlow = ((unsigned)p.x) >> 22;
            int grow = growbase + (int)rlow;
            if (grow < N_ENT) {
                int t = p.x & 0x1FFFF;
                int r = (p.x >> 17) & 15;
                float lg = (float)Pu16[(size_t)t * 16 + r]
                         + Pv32[(size_t)grow * 16 + r] + c16[r];
                lg = lg >= 0.f ? lg : 0.01f * lg;
                // softmax is shift-invariant; |logit| << 1 so skip segment-max
                float exv = expf(lg);
                seg[i].y = __float_as_int(exv);
                atomicAdd(&rsum[rlow], exv);
            }
        }
        __syncthreads();
        rsum[tid] = 1.f / rsum[tid];   // unused for CF/empty rows
        __syncthreads();
        for (int i = tid; i < bsize; i += 256) {
            int2 p = seg[i];
            unsigned rlow = ((unsigned)p.x) >> 22;
            if (growbase + (int)rlow < N_ENT)
                p.y = __float_as_int(__int_as_float(p.y) * rsum[rlow]);
            pairbuf[base + i] = p;
        }
    } else {
        for (int i = base + tid; i < endo; i += 256) {
            int2 p = bufA[i];
            unsigned rlow = ((unsigned)p.x) >> 22;
            int slot = atomicAdd(&rcur[rlow], 1);
            pairbuf[base + slot] = p;
        }
        __syncthreads();
        for (int i = base + tid; i < endo; i += 256) {
            int2 p = pairbuf[i];
            unsigned rlow = ((unsigned)p.x) >> 22;
            int grow = growbase + (int)rlow;
            if (grow < N_ENT) {
                int t = p.x & 0x1FFFF;
                int r = (p.x >> 17) & 15;
                float lg = (float)Pu16[(size_t)t * 16 + r]
                         + Pv32[(size_t)grow * 16 + r] + c16[r];
                lg = lg >= 0.f ? lg : 0.01f * lg;
                float exv = expf(lg);
                pairbuf[i].y = __float_as_int(exv);
                atomicAdd(&rsum[rlow], exv);
            }
        }
        __syncthreads();
        rsum[tid] = 1.f / rsum[tid];
        __syncthreads();
        for (int i = base + tid; i < endo; i += 256) {
            int2 p = pairbuf[i];
            unsigned rlow = ((unsigned)p.x) >> 22;
            if (growbase + (int)rlow < N_ENT)
                pairbuf[i].y = __float_as_int(__int_as_float(p.y) * rsum[rlow]);
        }
    }
}

// ---------------------------------------------------------------------------
// Pack Wa,Wb into fp16 MFMA B-fragment layout (16 KB).
// ---------------------------------------------------------------------------
__global__ void k_wcvt(const float* __restrict__ Wa, const float* __restrict__ Wb,
                       _Float16* __restrict__ wpack) {
    int i = blockIdx.x * 256 + threadIdx.x;
    if (i >= 8192) return;
    int m = i >> 12;
    int rem = i & 4095;
    int kstep = rem >> 11;
    int rem2 = rem & 2047;
    int ntile = rem2 >> 9;
    int rem3 = rem2 & 511;
    int lane = rem3 >> 3;
    int j = rem3 & 7;
    int k = kstep * 32 + (lane >> 4) * 8 + j;
    int n = ntile * 16 + (lane & 15);
    const float* W = m ? Wb : Wa;
    wpack[i] = (_Float16)W[k * 64 + n];
}

// ---------------------------------------------------------------------------
// MERGED PAIRED-ROW CSR SpMM v3 (round-9: unroll-8 + cached pairbuf, 95us,
// 3.65 TB/s — at the converged random-gather pattern ceiling; line closed).
// ---------------------------------------------------------------------------
__global__ __launch_bounds__(256) void k_spmm2(const int* __restrict__ rowptr,
        const int2* __restrict__ pairbuf, const _Float16* __restrict__ xkg,
        const _Float16* __restrict__ xcf, _Float16* __restrict__ outkg,
        _Float16* __restrict__ outcf, int row_begin) {
    int wid0 = (blockIdx.x * 256 + threadIdx.x) >> 6;
    int wpair = __builtin_amdgcn_readfirstlane(wid0);
    int lane = threadIdx.x & 63;
    int half = lane >> 5;
    int sub = lane & 31;
    int row = row_begin + wpair * 2 + half;
    if (row >= N_ROWS) return;
    int d0 = sub * 2;
    bool kg = row < N_ENT;
    const _Float16* xb = (kg ? xkg : xcf) + d0;
    int cmask = kg ? 0x1FFFF : 0x3FFFF;
    _Float16* ob = kg ? (outkg + (size_t)row * DD)
                      : (outcf + (size_t)(row - N_ENT) * DD);
    int s = rowptr[row], e = rowptr[row + 1];
    float a00 = 0.f, a01 = 0.f, a10 = 0.f, a11 = 0.f;
    float a20 = 0.f, a21 = 0.f, a30 = 0.f, a31 = 0.f;
    float a40 = 0.f, a41 = 0.f, a50 = 0.f, a51 = 0.f;
    float a60 = 0.f, a61 = 0.f, a70 = 0.f, a71 = 0.f;
    int i = s;
    for (; i + 8 <= e; i += 8) {
        int2 p0 = pairbuf[i],     p1 = pairbuf[i + 1];
        int2 p2 = pairbuf[i + 2], p3 = pairbuf[i + 3];
        int2 p4 = pairbuf[i + 4], p5 = pairbuf[i + 5];
        int2 p6 = pairbuf[i + 6], p7 = pairbuf[i + 7];
        h2v g0 = *(const h2v*)(xb + (size_t)(p0.x & cmask) * DD);
        h2v g1 = *(const h2v*)(xb + (size_t)(p1.x & cmask) * DD);
        h2v g2 = *(const h2v*)(xb + (size_t)(p2.x & cmask) * DD);
        h2v g3 = *(const h2v*)(xb + (size_t)(p3.x & cmask) * DD);
        h2v g4 = *(const h2v*)(xb + (size_t)(p4.x & cmask) * DD);
        h2v g5 = *(const h2v*)(xb + (size_t)(p5.x & cmask) * DD);
        h2v g6 = *(const h2v*)(xb + (size_t)(p6.x & cmask) * DD);
        h2v g7 = *(const h2v*)(xb + (size_t)(p7.x & cmask) * DD);
        float w0 = __int_as_float(p0.y), w1 = __int_as_float(p1.y);
        float w2 = __int_as_float(p2.y), w3 = __int_as_float(p3.y);
        float w4 = __int_as_float(p4.y), w5 = __int_as_float(p5.y);
        float w6 = __int_as_float(p6.y), w7 = __int_as_float(p7.y);
        a00 = fmaf(w0, (float)g0[0], a00); a01 = fmaf(w0, (float)g0[1], a01);
        a10 = fmaf(w1, (float)g1[0], a10); a11 = fmaf(w1, (float)g1[1], a11);
        a20 = fmaf(w2, (float)g2[0], a20); a21 = fmaf(w2, (float)g2[1], a21);
        a30 = fmaf(w3, (float)g3[0], a30); a31 = fmaf(w3, (float)g3[1], a31);
        a40 = fmaf(w4, (float)g4[0], a40); a41 = fmaf(w4, (float)g4[1], a41);
        a50 = fmaf(w5, (float)g5[0], a50); a51 = fmaf(w5, (float)g5[1], a51);
        a60 = fmaf(w6, (float)g6[0], a60); a61 = fmaf(w6, (float)g6[1], a61);
        a70 = fmaf(w7, (float)g7[0], a70); a71 = fmaf(w7, (float)g7[1], a71);
    }
    for (; i + 2 <= e; i += 2) {
        int2 p0 = pairbuf[i], p1 = pairbuf[i + 1];
        h2v g0 = *(const h2v*)(xb + (size_t)(p0.x & cmask) * DD);
        h2v g1 = *(const h2v*)(xb + (size_t)(p1.x & cmask) * DD);
        float w0 = __int_as_float(p0.y), w1 = __int_as_float(p1.y);
        a00 = fmaf(w0, (float)g0[0], a00); a01 = fmaf(w0, (float)g0[1], a01);
        a10 = fmaf(w1, (float)g1[0], a10); a11 = fmaf(w1, (float)g1[1], a11);
    }
    if (i < e) {
        int2 p0 = pairbuf[i];
        h2v g0 = *(const h2v*)(xb + (size_t)(p0.x & cmask) * DD);
        float w0 = __int_as_float(p0.y);
        a00 = fmaf(w0, (float)g0[0], a00); a01 = fmaf(w0, (float)g0[1], a01);
    }
    float r0 = ((a00 + a10) + (a20 + a30)) + ((a40 + a50) + (a60 + a70));
    float r1 = ((a01 + a11) + (a21 + a31)) + ((a41 + a51) + (a61 + a71));
    h2v st; st[0] = (_Float16)r0; st[1] = (_Float16)r1;
    *(h2v*)(ob + d0) = st;
}

// ---------------------------------------------------------------------------
// Entity gate via MFMA (one wave = 16 rows), FUSED with user passthrough copy:
// blocks >= ngate copy ig16 user rows into dual16 (half8).
// acc = kg@Wa + ig@Wb in one accumulator chain.
// C/D: col=lane&15, row=(lane>>4)*4+reg [m89-verified].
// ---------------------------------------------------------------------------
__global__ __launch_bounds__(256) void k_gate3(const _Float16* __restrict__ kg16,
        const _Float16* __restrict__ ig16, const _Float16* __restrict__ wpack,
        _Float16* __restrict__ dual16, int ngate) {
    __shared__ _Float16 sw[8192];
    if ((int)blockIdx.x >= ngate) {
        int i = ((int)blockIdx.x - ngate) * 256 + threadIdx.x;
        if (i < N_USR * DD / 8) {
            size_t o = (size_t)N_ENT * DD / 8 + i;
            ((half8*)dual16)[o] = ((const half8*)ig16)[o];
        }
        return;
    }
    for (int i = threadIdx.x * 8; i < 8192; i += 256 * 8)
        *(half8*)(sw + i) = *(const half8*)(wpack + i);
    __syncthreads();
    int lane = threadIdx.x & 63;
    int wv = (blockIdx.x * 256 + threadIdx.x) >> 6;
    int row0 = wv * 16;
    if (row0 >= N_ENT) return;
    int m = lane & 15;
    int quad = lane >> 4;

    const _Float16* kgr = kg16 + (size_t)(row0 + m) * DD + quad * 8;
    const _Float16* igr = ig16 + (size_t)(row0 + m) * DD + quad * 8;
    half8 akg0 = *(const half8*)(kgr);
    half8 akg1 = *(const half8*)(kgr + 32);
    half8 aig0 = *(const half8*)(igr);
    half8 aig1 = *(const half8*)(igr + 32);

    floatx4 acc[4];
#pragma unroll
    for (int t = 0; t < 4; ++t) {
        half8 bA0 = *(const half8*)(sw + 0 * 4096 + 0 * 2048 + t * 512 + lane * 8);
        half8 bA1 = *(const half8*)(sw + 0 * 4096 + 1 * 2048 + t * 512 + lane * 8);
        half8 bB0 = *(const half8*)(sw + 1 * 4096 + 0 * 2048 + t * 512 + lane * 8);
        half8 bB1 = *(const half8*)(sw + 1 * 4096 + 1 * 2048 + t * 512 + lane * 8);
        floatx4 c = {0.f, 0.f, 0.f, 0.f};
        c = __builtin_amdgcn_mfma_f32_16x16x32_f16(akg0, bA0, c, 0, 0, 0);
        c = __builtin_amdgcn_mfma_f32_16x16x32_f16(akg1, bA1, c, 0, 0, 0);
        c = __builtin_amdgcn_mfma_f32_16x16x32_f16(aig0, bB0, c, 0, 0, 0);
        c = __builtin_amdgcn_mfma_f32_16x16x32_f16(aig1, bB1, c, 0, 0, 0);
        acc[t] = c;
    }

#pragma unroll
    for (int t = 0; t < 4; ++t) {
#pragma unroll
        for (int r = 0; r < 4; ++r) {
            int row = quad * 4 + r;
            int col = t * 16 + m;
            size_t o = (size_t)(row0 + row) * DD + col;
            float kv = (float)kg16[o];
            float cv = (float)ig16[o];
            float g = 1.f / (1.f + expf(-acc[t][r]));
            dual16[o] = (_Float16)(g * kv + (1.f - g) * cv);
        }
    }
}

// init: dual16 = fp16(embed)
__global__ void k_init(const float* __restrict__ embed, _Float16* __restrict__ dual16) {
    int i = blockIdx.x * blockDim.x + threadIdx.x;
    if (i >= N_TOT * DD) return;
    dual16[i] = (_Float16)embed[i];
}

// ---------------------------------------------------------------------------
// out[u,j] = sums[user_ids[u]] . sums[item_ids[j]],
// sums[row] = embed[row] + ig0[row] + ig1[row] + ig2[row] (reconstructed).
// 256 blocks: 32 user-groups (32 users) x 8 item-chunks (256 items).
// ---------------------------------------------------------------------------
__global__ __launch_bounds__(256) void k_out(const float* __restrict__ embed,
        const _Float16* __restrict__ ig0, const _Float16* __restrict__ ig1,
        const _Float16* __restrict__ ig2, const int* __restrict__ user_ids,
        const int* __restrict__ item_ids, float* __restrict__ out) {
    __shared__ float uvec[32 * DD];
    int ug = blockIdx.x >> 3;
    int qi = blockIdx.x & 7;
    int ub = ug * 32;
    for (int i = threadIdx.x; i < 32 * DD; i += 256) {
        int uu = i >> 6, d = i & 63;
        size_t o = (size_t)user_ids[ub + uu] * DD + d;
        uvec[i] = embed[o] + (float)ig0[o] + (float)ig1[o] + (float)ig2[o];
    }
    __syncthreads();
    int jbase = qi * 256;
    for (int j = threadIdx.x; j < 256; j += 256) {
        size_t ro = (size_t)item_ids[jbase + j] * DD;
        float acc[32];
#pragma unroll
        for (int u = 0; u < 32; ++u) acc[u] = 0.f;
        for (int d = 0; d < DD; d += 4) {
            float4 ev = *(const float4*)(embed + ro + d);
            half4 h0 = *(const half4*)(ig0 + ro + d);
            half4 h1 = *(const half4*)(ig1 + ro + d);
            half4 h2 = *(const half4*)(ig2 + ro + d);
            float iv0 = ev.x + (float)h0[0] + (float)h1[0] + (float)h2[0];
            float iv1 = ev.y + (float)h0[1] + (float)h1[1] + (float)h2[1];
            float iv2 = ev.z + (float)h0[2] + (float)h1[2] + (float)h2[2];
            float iv3 = ev.w + (float)h0[3] + (float)h1[3] + (float)h2[3];
#pragma unroll
            for (int u = 0; u < 32; ++u) {
                acc[u] = fmaf(iv0, uvec[u * DD + d + 0], acc[u]);
                acc[u] = fmaf(iv1, uvec[u * DD + d + 1], acc[u]);
                acc[u] = fmaf(iv2, uvec[u * DD + d + 2], acc[u]);
                acc[u] = fmaf(iv3, uvec[u * DD + d + 3], acc[u]);
            }
        }
#pragma unroll
        for (int u = 0; u < 32; ++u)
            out[(size_t)(ub + u) * 2048 + jbase + j] = acc[u];
    }
}

extern "C" void kernel_launch(void* const* d_in, const int* in_sizes, int n_in,
                              void* d_out, int out_size, void* d_ws, size_t ws_size,
                              hipStream_t stream) {
    const float* embed   = (const float*)d_in[0];
    const float* rel     = (const float*)d_in[1];
    const float* Wk_w    = (const float*)d_in[2];
    const float* Wk_b    = (const float*)d_in[3];
    const float* Wa      = (const float*)d_in[4];
    const float* Wb      = (const float*)d_in[5];
    const int*   kg_h    = (const int*)d_in[6];
    const int*   kg_t    = (const int*)d_in[7];
    const int*   kg_r    = (const int*)d_in[8];
    const int*   ain_row = (const int*)d_in[9];
    const int*   ain_col = (const int*)d_in[10];
    const float* ain_val = (const float*)d_in[11];
    const int*   user_ids = (const int*)d_in[12];
    const int*   item_ids = (const int*)d_in[13];
    int E_KG = in_sizes[6];
    int E_CF = in_sizes[9];
    int E_TOT = E_KG + E_CF;
    float* out = (float*)d_out;

    int NT  = (E_TOT + SORT_T - 1) / SORT_T;   // phase-1 tiles (733)
    int NTC = NBUKU * NT;                       // scan length (~716K)

    float* ws = (float*)d_ws;
    size_t off = 0;
    float* uvr       = ws + off; off += 16 * 132;
    // Puv slot (100000*32 floats = 12.8MB) now carved into:
    //   Pv32 [N_ENT][16] fp32 (6.4MB) + Pu16 [N_ENT][16] fp16 (3.2MB).
    float* Pv32      = ws + off;
    _Float16* Pu16   = (_Float16*)(ws + off + (size_t)N_ENT * 16);
    off += (size_t)N_ENT * 32;
    int*   rowptr    = (int*)(ws + off); off += N_ROWS + 4;
    int*   tilecnt   = (int*)(ws + off); off += (size_t)NTC + 4;
    int*   tilescan  = (int*)(ws + off); off += (size_t)NTC + 4;
    int*   bsum      = (int*)(ws + off); off += 1024;
    int2*  pairbuf   = (int2*)(ws + off); off += 2 * (size_t)E_TOT;   // final (row-sorted)
    _Float16* dual16 = (_Float16*)(ws + off); off += (size_t)N_TOT * DD / 2;
    _Float16* ig16_0 = (_Float16*)(ws + off); off += (size_t)N_TOT * DD / 2;
    _Float16* ig16_1 = (_Float16*)(ws + off); off += (size_t)N_TOT * DD / 2;
    _Float16* ig16_2 = (_Float16*)(ws + off); off += (size_t)N_TOT * DD / 2;
    _Float16* kg16A  = (_Float16*)(ws + off); off += (size_t)N_ENT * DD / 2;
    _Float16* kg16B  = (_Float16*)(ws + off); off += (size_t)N_ENT * DD / 2;
    _Float16* wpack  = (_Float16*)(ws + off); off += 8192 / 2;
    int2*  bufA      = (int2*)kg16A;   // alias: 24MB <= kg16A+kg16B (25.6MB); dead before layer0
    // upack aliases the HEAD of pairbuf (4 KB): written by k_uvpack, read by
    // k_proj, both strictly before k_sort_fine first writes pairbuf. Keeps the
    // ws footprint identical to the harness-verified round-0/1 layout (no tail
    // growth -> no OOB past ws_size).
    _Float16* upack  = (_Float16*)pairbuf;
    _Float16* ig_l[3] = {ig16_0, ig16_1, ig16_2};

    // --- attention precompute (needed by fused sort+softmax) ---
    // k_init first: dual16 (fp16 embed) feeds the MFMA k_proj.
    hipLaunchKernelGGL(k_init, dim3((N_TOT * DD + 255) / 256), dim3(256), 0, stream,
                       embed, dual16);
    hipLaunchKernelGGL(k_rel, dim3(16), dim3(128), 0, stream, Wk_w, Wk_b, rel, uvr);
    hipLaunchKernelGGL(k_uvpack, dim3(8), dim3(256), 0, stream, uvr, upack);
    hipLaunchKernelGGL(k_proj, dim3((N_ENT / 16 + 3) / 4), dim3(256), 0, stream,
                       dual16, upack, Pu16, Pv32);

    // --- binning sort: hist -> scan -> tile scatter -> fine sort + softmax ---
    hipLaunchKernelGGL(k_sort_hist, dim3(NT), dim3(256), 0, stream,
                       kg_h, ain_row, tilecnt, E_KG, E_TOT, NT);
    int nb = (NTC + SCAN_ITEMS - 1) / SCAN_ITEMS;   // ~700
    hipLaunchKernelGGL(k_blocksum, dim3(nb), dim3(SCAN_BLK), 0, stream, tilecnt, bsum, NTC);
    hipLaunchKernelGGL(k_bscan, dim3(1), dim3(1024), 0, stream, bsum, nb, tilescan + NTC);
    hipLaunchKernelGGL(k_scan_apply, dim3(nb), dim3(SCAN_BLK), 0, stream,
                       tilecnt, tilescan, bsum, NTC);
    hipLaunchKernelGGL(k_sort_scatter, dim3(NT), dim3(256), 0, stream,
                       kg_h, kg_t, kg_r, ain_row, ain_col, ain_val, tilescan,
                       bufA, E_KG, E_TOT, NT);
    hipLaunchKernelGGL(k_sort_fine, dim3(NBUKU), dim3(256), 0, stream,
                       tilescan, bufA, pairbuf, rowptr, Pu16, Pv32, uvr, NT);

    hipLaunchKernelGGL(k_wcvt, dim3(32), dim3(256), 0, stream, Wa, Wb, wpack);

    // --- 3 propagation layers; layers 0/1 use the MERGED KG+CF spmm ---
    const _Float16* cur16 = dual16;       // layer0 KG gather table = fp16 embed
    _Float16* kg16o = kg16A;
    _Float16* kg16alt = kg16B;
    int all_blocks = ((N_ROWS / 2) * 64 + 255) / 256;   // 31250
    int cf_blocks = ((N_TOT / 2) * 64 + 255) / 256;     // 18750
    int ngate = (N_ENT / 16 + 3) / 4;                   // 1563
    int nuc = (N_USR * DD / 8 + 255) / 256;             // 1563
    for (int layer = 0; layer < 3; ++layer) {
        if (layer < 2) {
            hipLaunchKernelGGL(k_spmm2, dim3(all_blocks), dim3(256), 0, stream,
                               rowptr, pairbuf, cur16, dual16, kg16o, ig_l[layer], 0);
            hipLaunchKernelGGL(k_gate3, dim3(ngate + nuc), dim3(256), 0, stream,
                               kg16o, ig_l[layer], wpack, dual16, ngate);
            cur16 = kg16o;
            kg16o = kg16alt;
            kg16alt = (_Float16*)cur16;
        } else {
            hipLaunchKernelGGL(k_spmm2, dim3(cf_blocks), dim3(256), 0, stream,
                               rowptr, pairbuf, dual16, dual16, kg16o, ig_l[layer], N_ENT);
        }
    }

    // --- final gather-GEMM 1024 x 2048 x 64 with on-the-fly sums ---
    hipLaunchKernelGGL(k_out, dim3(256), dim3(256), 0, stream,
                       embed, ig16_0, ig16_1, ig16_2, user_ids, item_ids, out);
}